// Round 4
// baseline (189.856 us; speedup 1.0000x reference)
//
#include <hip/hip_runtime.h>
#include <cstdint>

#define P_BOX 8732
#define NBOX_TOTAL 279424  // 32*8732
#define BATCH 32
#define NCLS 21
#define TOPK 200
#define NTH 256
#define NCH 9  // chunks of 1024 keys; chunk 8 partial (t < 135)
#define CAND_CAP 512
#define NBKT 2048
#define NORM 0xBC23D70Bu  // score_key(0.01f)+1 ; stored keys are pre-normalized
#define LIM (1u << 26)    // normalized key < LIM  <=>  eligible (score > 0.01)
#define CONF_F4 1466976   // 32*8732*21/4

typedef unsigned long long u64;

// monotonic float->u32 (total order), invertible
__device__ __forceinline__ uint32_t score_key(float m) {
  uint32_t b = __float_as_uint(m);
  return (b & 0x80000000u) ? ~b : (b | 0x80000000u);
}
__device__ __forceinline__ float key_score(uint32_t k) {
  uint32_t b = (k & 0x80000000u) ? (k ^ 0x80000000u) : ~k;
  return __uint_as_float(b);
}

// Exactly mirrors reference _decode (fp32).
__device__ __forceinline__ float4 decode_box(const float4 pr, const float4 lc) {
  float px = fmaxf(pr.x, 1e-6f), py = fmaxf(pr.y, 1e-6f);
  float pw = fmaxf(pr.z, 1e-6f), ph = fmaxf(pr.w, 1e-6f);
  float cx = px + lc.x * 0.1f * pw;
  float cy = py + lc.y * 0.1f * ph;
  float lw = fminf(fmaxf(lc.z * 0.2f, -4.0f), 4.0f);
  float lh = fminf(fmaxf(lc.w * 0.2f, -4.0f), 4.0f);
  float w = pw * expf(lw);
  float h = ph * expf(lh);
  float4 r;
  r.x = fminf(fmaxf(cx - 0.5f * w, 0.0f), 1.0f);
  r.y = fminf(fmaxf(cy - 0.5f * h, 0.0f), 1.0f);
  r.z = fminf(fmaxf(cx + 0.5f * w, 0.0f), 1.0f);
  r.w = fminf(fmaxf(cy + 0.5f * h, 0.0f), 1.0f);
  return r;
}

// Prep: 256 boxes/block. Stage conf in LDS (coalesced float4 global loads;
// stride-21 LDS reads are conflict-free since 21 is odd). Emit normalized
// masked score-keys, class-major: keys[(b*20 + c-1)*P_BOX + p].
__global__ __launch_bounds__(256) void prep_kernel(
    const float* __restrict__ loc, const float* __restrict__ conf,
    const float* __restrict__ priors, uint32_t* __restrict__ keys) {
  __shared__ float s_conf[256 * 21];  // 21504 B
  const int t = threadIdx.x;
  const int blk = blockIdx.x;
  const float4* cf4 = (const float4*)conf;
  size_t base4 = (size_t)blk * 1344;
#pragma unroll
  for (int i = t; i < 1344; i += 256) {
    size_t g4 = base4 + i;
    if (g4 < CONF_F4) ((float4*)s_conf)[i] = cf4[g4];
  }
  __syncthreads();
  int g = blk * 256 + t;
  if (g >= NBOX_TOTAL) return;
  int b = g / P_BOX, p = g - b * P_BOX;
  float x[NCLS];
  float mx = -1e30f;
#pragma unroll
  for (int i = 0; i < NCLS; ++i) {
    float v = fminf(fmaxf(s_conf[t * 21 + i], -100.0f), 100.0f);
    x[i] = v;
    mx = fmaxf(mx, v);
  }
  float s = 0.0f;
#pragma unroll
  for (int i = 0; i < NCLS; ++i) {
    x[i] = expf(x[i] - mx);
    s += x[i];
  }
  float4 bx = decode_box(((const float4*)priors)[p], ((const float4*)loc)[g]);
  bool bok = (bx.z > bx.x + 1e-6f) && (bx.w > bx.y + 1e-6f);
#pragma unroll
  for (int ci = 1; ci < NCLS; ++ci) {
    float sc = x[ci] / s;  // division, matching reference softmax
    float m = (bok && sc > 0.01f) ? sc : -1.0f;
    keys[((size_t)(b * 20) + (ci - 1)) * P_BOX + p] = score_key(m) - NORM;
  }
}

__device__ __forceinline__ int cnt_ge(const uint32_t* kv, uint32_t X) {
  int n = 0;
#pragma unroll
  for (int j = 0; j < NCH * 4; ++j) n += (kv[j] >= X && kv[j] < LIM) ? 1 : 0;
  return n;
}
__device__ __forceinline__ int cnt_eq_idx(const uint32_t* kv, int t, uint32_t T, uint32_t I) {
  int n = 0;
#pragma unroll
  for (int ch = 0; ch < NCH; ++ch) {
#pragma unroll
    for (int e = 0; e < 4; ++e) {
      int p = ch * 1024 + t * 4 + e;
      n += (kv[ch * 4 + e] == T && (uint32_t)(P_BOX - p) >= I) ? 1 : 0;
    }
  }
  return n;
}

// Block-wide sum, ONE barrier per call (3-slot rotation).
__device__ __forceinline__ int block_count(int v, int t, int* s_cnt, int& it) {
#pragma unroll
  for (int o = 32; o > 0; o >>= 1) v += __shfl_down(v, o, 64);
  int slot = it % 3;
  if (t == 0) s_cnt[(it + 1) % 3] = 0;
  if ((t & 63) == 0) atomicAdd(&s_cnt[slot], v);
  __syncthreads();
  int r = s_cnt[slot];
  ++it;
  return r;
}

// Largest bucket B (of NBKT) with suffix-count >= need; returns
// {B, M=suffix(B), above=suffix(B+1)}. If total < need: {0, total, 0}.
__device__ __forceinline__ int3 select_bucket(const int* s_hist, int* s_S,
                                              int* s_wt, int* s_res, int need,
                                              int t) {
  const int BPT = NBKT / NTH;  // 8
  int base = t * BPT;
  int ps = 0;
#pragma unroll
  for (int i = 0; i < BPT; ++i) ps += s_hist[base + i];
  int l = t & 63, w = t >> 6;
  int v = ps;
#pragma unroll
  for (int off = 1; off < 64; off <<= 1) {
    int o = __shfl_down(v, off, 64);
    v += (l + off < 64) ? o : 0;  // inclusive suffix scan within wave
  }
  if (l == 0) s_wt[w] = v;
  __syncthreads();
  int hi = 0;
#pragma unroll
  for (int w2 = 0; w2 < NTH / 64; ++w2) hi += (w2 > w) ? s_wt[w2] : 0;
  int S = v + hi;  // suffix-count from bucket base = t*BPT
  s_S[t] = S;
  __syncthreads();
  if (t == 0 && s_S[0] < need) {
    s_res[0] = 0; s_res[1] = s_S[0]; s_res[2] = 0;
  } else if (s_S[t] >= need && (t == NTH - 1 || s_S[t + 1] < need)) {
    int suf = (t == NTH - 1) ? 0 : s_S[t + 1];
    int B = base, M = 0;
    for (int j = base + BPT - 1; j >= base; --j) {
      suf += s_hist[j];
      if (suf >= need) { B = j; M = suf; break; }
    }
    s_res[0] = B; s_res[1] = M; s_res[2] = M - s_hist[B];
  }
  __syncthreads();
  return make_int3(s_res[0], s_res[1], s_res[2]);
}

template <bool USE_WS>
__global__ __launch_bounds__(256) void nms_kernel(
    const float* __restrict__ loc, const float* __restrict__ conf,
    const float* __restrict__ priors, const uint32_t* __restrict__ keys,
    float* __restrict__ out) {
  const int t = threadIdx.x;
  const int task = blockIdx.x;  // b*21 + c
  const int b = task / NCLS, c = task - b * NCLS;
  float* ob = out + (size_t)task * TOPK * 5;

  if (c == 0) {  // background class: all-zero rows
    float4 z = make_float4(0.f, 0.f, 0.f, 0.f);
    for (int i = t; i < TOPK * 5 / 4; i += NTH) ((float4*)ob)[i] = z;
    return;
  }

  __shared__ alignas(16) int s_hist[NBKT];      // 8 KB; aliased by s_sup (6.4 KB)
  __shared__ alignas(16) u64 s_cand[CAND_CAP];  // 4 KB; aliased by s_S / s_rows
  __shared__ u64 s_sel[TOPK];
  __shared__ float4 s_box[256];
  __shared__ float s_area[256];
  __shared__ float s_score[256];
  __shared__ u64 s_alive[4];
  __shared__ short s_kept[TOPK];
  __shared__ int s_wt[NTH / 64];
  __shared__ int s_res[3];
  __shared__ int s_cnt[3];
  __shared__ int s_m;
  u64* s_sup = (u64*)s_hist;       // 200*4 u64, used after selection
  int* s_S = (int*)s_cand;         // 256 ints, selection only
  float* s_rows = (float*)s_cand;  // 1000 floats, epilogue staging

  if (t == 0) { s_cnt[0] = 0; s_cnt[1] = 0; s_cnt[2] = 0; s_m = 0; }
  for (int i = t; i < NBKT; i += NTH) s_hist[i] = 0;

  // ---- load this (b,c)'s 8732 normalized keys into registers (36/thread) ----
  uint32_t kv[NCH * 4];
  if (USE_WS) {
    const uint4* kp = (const uint4*)(keys + (size_t)(b * 20 + (c - 1)) * P_BOX);
#pragma unroll
    for (int ch = 0; ch < 8; ++ch) {
      uint4 v = kp[ch * 256 + t];
      kv[ch * 4 + 0] = v.x; kv[ch * 4 + 1] = v.y;
      kv[ch * 4 + 2] = v.z; kv[ch * 4 + 3] = v.w;
    }
    if (t < 135) {
      uint4 v = kp[2048 + t];
      kv[32] = v.x; kv[33] = v.y; kv[34] = v.z; kv[35] = v.w;
    } else {
      kv[32] = LIM; kv[33] = LIM; kv[34] = LIM; kv[35] = LIM;
    }
  } else {
    for (int ch = 0; ch < NCH; ++ch) {
      int p0 = ch * 1024 + 4 * t;
#pragma unroll
      for (int e = 0; e < 4; ++e) {
        int p = p0 + e;
        uint32_t k = LIM;
        if (p < P_BOX) {
          const float* cf = conf + (size_t)(b * P_BOX + p) * NCLS;
          float x[NCLS];
          float mx = -1e30f;
#pragma unroll
          for (int i = 0; i < NCLS; ++i) {
            float v = fminf(fmaxf(cf[i], -100.0f), 100.0f);
            x[i] = v;
            mx = fmaxf(mx, v);
          }
          float ssum = 0.0f, ec = 0.0f;
#pragma unroll
          for (int i = 0; i < NCLS; ++i) {
            float ex = expf(x[i] - mx);
            ssum += ex;
            if (i == c) ec = ex;
          }
          float sc = ec / ssum;
          float4 bx = decode_box(((const float4*)priors)[p],
                                 ((const float4*)loc)[(size_t)b * P_BOX + p]);
          bool valid = (sc > 0.01f) && (bx.z > bx.x + 1e-6f) && (bx.w > bx.y + 1e-6f);
          k = score_key(valid ? sc : -1.0f) - NORM;
        }
        kv[ch * 4 + e] = k;
      }
    }
  }
  __syncthreads();

  // ---- pass 1: 2048-bucket histogram of key bits [25:15] ----
#pragma unroll
  for (int j = 0; j < NCH * 4; ++j)
    if (kv[j] < LIM) atomicAdd(&s_hist[kv[j] >> 15], 1);
  __syncthreads();
  int3 r1 = select_bucket(s_hist, s_S, s_wt, s_res, TOPK, t);
  uint32_t Tp = (uint32_t)r1.x << 15;
  int M = r1.y;
  bool ex = false;
  uint32_t Tex = 0, I = 0;

  if (M > CAND_CAP) {  // rare: refine within bucket (width-16 sub-buckets)
    uint32_t B1 = (uint32_t)r1.x;
    int above1 = r1.z;
    __syncthreads();
    for (int i = t; i < NBKT; i += NTH) s_hist[i] = 0;
    __syncthreads();
#pragma unroll
    for (int j = 0; j < NCH * 4; ++j)
      if (kv[j] < LIM && (kv[j] >> 15) == B1)
        atomicAdd(&s_hist[(kv[j] >> 4) & (NBKT - 1)], 1);
    __syncthreads();
    int3 r2 = select_bucket(s_hist, s_S, s_wt, s_res, TOPK - above1, t);
    Tp = (B1 << 15) + ((uint32_t)r2.x << 4);
    M = above1 + r2.y;
    if (M > CAND_CAP) {  // pathological ties: exact key + index refinement
      int it = 0;
      uint32_t lo = Tp, hi = LIM;
      while (hi - lo > 1) {
        uint32_t mid = lo + ((hi - lo) >> 1);
        int cnt = block_count(cnt_ge(kv, mid), t, s_cnt, it);
        if (cnt >= TOPK) lo = mid; else hi = mid;
      }
      Tex = lo;
      int G = block_count(cnt_ge(kv, Tex + 1), t, s_cnt, it);
      int R = TOPK - G;  // >= 1
      uint32_t lo2 = 1, hi2 = P_BOX + 1;
      while (hi2 - lo2 > 1) {
        uint32_t mid = lo2 + ((hi2 - lo2) >> 1);
        int cnt = block_count(cnt_eq_idx(kv, t, Tex, mid), t, s_cnt, it);
        if (cnt >= R) lo2 = mid; else hi2 = mid;
      }
      I = lo2;
      ex = true;  // M becomes exactly 200 at gather
    }
  }
  __syncthreads();  // s_S (alias s_cand) dead; safe to gather

  // ---- gather candidates (packed key|P-p for exact total order) ----
#pragma unroll
  for (int ch = 0; ch < NCH; ++ch) {
#pragma unroll
    for (int e = 0; e < 4; ++e) {
      uint32_t k = kv[ch * 4 + e];
      if (k < LIM) {
        int p = ch * 1024 + 4 * t + e;
        bool take = ex ? (k > Tex || (k == Tex && (uint32_t)(P_BOX - p) >= I))
                       : (k >= Tp);
        if (take) {
          int ix = atomicAdd(&s_m, 1);
          if (ix < CAND_CAP) s_cand[ix] = ((u64)k << 32) | (uint32_t)(P_BOX - p);
        }
      }
    }
  }
  __syncthreads();
  M = min(s_m, CAND_CAP);
  int nsel = min(M, TOPK);

  // ---- rank (exact order; ties by smaller p), 8-wide pipelined reads ----
  for (int ci = t; ci < M; ci += NTH) {
    u64 mine = s_cand[ci];
    int r = 0;
    int j = 0;
    for (; j + 8 <= M; j += 8) {  // 8 independent LDS loads per group
      u64 a0 = s_cand[j + 0], a1 = s_cand[j + 1], a2 = s_cand[j + 2],
          a3 = s_cand[j + 3], a4 = s_cand[j + 4], a5 = s_cand[j + 5],
          a6 = s_cand[j + 6], a7 = s_cand[j + 7];
      r += (a0 > mine) + (a1 > mine) + (a2 > mine) + (a3 > mine) +
           (a4 > mine) + (a5 > mine) + (a6 > mine) + (a7 > mine);
    }
    for (; j < M; ++j) r += (s_cand[j] > mine) ? 1 : 0;
    if (r < TOPK) s_sel[r] = mine;
  }
  __syncthreads();

  // ---- decode selected boxes; zero-init suppression masks ----
  if (t < nsel) {
    u64 w = s_sel[t];
    uint32_t k = (uint32_t)(w >> 32);
    int p = P_BOX - (int)(uint32_t)(w & 0xFFFFFFFFull);
    float4 bx = decode_box(((const float4*)priors)[p],
                           ((const float4*)loc)[(size_t)b * P_BOX + p]);
    s_box[t] = bx;
    s_area[t] = (bx.z - bx.x) * (bx.w - bx.y);
    s_score[t] = key_score(k + NORM);
  } else {
    s_box[t] = make_float4(0.f, 0.f, 0.f, 0.f);
    s_area[t] = 0.f;
    s_score[t] = 0.f;
  }
  for (int i = t; i < TOPK * 4; i += NTH) s_sup[i] = 0ull;
  __syncthreads();

  // ---- suppression bitmasks via ballot (4 waves, row-strided, prefetched) ----
  {
    int wv = t >> 6, l = t & 63;
    float4 bj[4];
    float aj[4];
#pragma unroll
    for (int cc = 0; cc < 4; ++cc) {
      bj[cc] = s_box[cc * 64 + l];
      aj[cc] = s_area[cc * 64 + l];
    }
    int cmax = (nsel + 63) >> 6;
    float4 bi;
    float ai;
    if (wv < nsel) { bi = s_box[wv]; ai = s_area[wv]; }
    for (int i = wv; i < nsel; i += 4) {
      int in_ = i + 4;
      float4 bn = bi;
      float an = ai;
      if (in_ < nsel) { bn = s_box[in_]; an = s_area[in_]; }  // prefetch next row
      int c0 = i >> 6;
      for (int cc = c0; cc < cmax; ++cc) {
        int j = cc * 64 + l;
        float lx = fmaxf(bi.x, bj[cc].x), ly = fmaxf(bi.y, bj[cc].y);
        float rx = fminf(bi.z, bj[cc].z), ry = fminf(bi.w, bj[cc].w);
        float iw = fmaxf(rx - lx, 0.0f), ih = fmaxf(ry - ly, 0.0f);
        float inter = iw * ih;
        float uni = ai + aj[cc] - inter;
        float iou = inter / fmaxf(uni, 1e-12f);
        bool sup = (j > i) && (j < nsel) && (iou > 0.45f);
        u64 m = __ballot(sup);
        if (l == 0) s_sup[i * 4 + cc] = m;
      }
      bi = bn;
      ai = an;
    }
  }
  __syncthreads();

  // ---- serial greedy walk, software-pipelined row prefetch ----
  if (t == 0) {
    u64 aw0, aw1, aw2, aw3;
    {
      int r0 = nsel, r1 = nsel - 64, r2 = nsel - 128, r3 = nsel - 192;
      aw0 = r0 >= 64 ? ~0ull : (r0 <= 0 ? 0ull : ((1ull << r0) - 1));
      aw1 = r1 >= 64 ? ~0ull : (r1 <= 0 ? 0ull : ((1ull << r1) - 1));
      aw2 = r2 >= 64 ? ~0ull : (r2 <= 0 ? 0ull : ((1ull << r2) - 1));
      aw3 = r3 >= 64 ? ~0ull : (r3 <= 0 ? 0ull : ((1ull << r3) - 1));
    }
    u64 p0 = s_sup[0], p1 = s_sup[1], p2 = s_sup[2], p3 = s_sup[3];
    for (int i = 0; i < nsel; ++i) {
      u64 c0 = p0, c1 = p1, c2 = p2, c3 = p3;
      int j = i + 1;
      if (j < nsel) {
        p0 = s_sup[j * 4 + 0]; p1 = s_sup[j * 4 + 1];
        p2 = s_sup[j * 4 + 2]; p3 = s_sup[j * 4 + 3];
      }
      int w = i >> 6;
      u64 cur = (w == 0) ? aw0 : (w == 1) ? aw1 : (w == 2) ? aw2 : aw3;
      if ((cur >> (i & 63)) & 1ull) {
        aw0 &= ~c0; aw1 &= ~c1; aw2 &= ~c2; aw3 &= ~c3;
      }
    }
    s_alive[0] = aw0; s_alive[1] = aw1; s_alive[2] = aw2; s_alive[3] = aw3;
  }
  __syncthreads();

  // ---- compact kept to front via popcount ranks ----
  u64 w0 = s_alive[0], w1 = s_alive[1], w2 = s_alive[2], w3 = s_alive[3];
  int pc0 = __popcll(w0), pc01 = pc0 + __popcll(w1), pc012 = pc01 + __popcll(w2);
  int nk = pc012 + __popcll(w3);
  if (t < nsel) {
    int word = t >> 6, bit = t & 63;
    u64 wt = (word == 0) ? w0 : (word == 1) ? w1 : (word == 2) ? w2 : w3;
    if ((wt >> bit) & 1ull) {
      int base = (word == 0) ? 0 : (word == 1) ? pc0 : (word == 2) ? pc01 : pc012;
      int r = base + __popcll(wt & ((1ull << bit) - 1ull));
      s_kept[r] = (short)t;
    }
  }
  __syncthreads();

  // ---- stage rows in LDS, then coalesced float4 store ----
  if (t < TOPK) {
    float r0 = 0.f, r1 = 0.f, r2 = 0.f, r3 = 0.f, r4 = 0.f;
    if (t < nk) {
      int j = s_kept[t];
      r0 = s_score[j];
      float4 bx = s_box[j];
      r1 = bx.x; r2 = bx.y; r3 = bx.z; r4 = bx.w;
    }
    s_rows[t * 5 + 0] = r0; s_rows[t * 5 + 1] = r1; s_rows[t * 5 + 2] = r2;
    s_rows[t * 5 + 3] = r3; s_rows[t * 5 + 4] = r4;
  }
  __syncthreads();
  for (int i = t; i < TOPK * 5 / 4; i += NTH)
    ((float4*)ob)[i] = ((float4*)s_rows)[i];
}

extern "C" void kernel_launch(void* const* d_in, const int* in_sizes, int n_in,
                              void* d_out, int out_size, void* d_ws, size_t ws_size,
                              hipStream_t stream) {
  (void)in_sizes;
  (void)n_in;
  (void)out_size;
  const float* loc = (const float*)d_in[0];     // [B,P,4]
  const float* conf = (const float*)d_in[1];    // [B,P,21]
  const float* priors = (const float*)d_in[2];  // [P,4]
  float* out = (float*)d_out;                   // [B,21,200,5]

  size_t keys_bytes = (size_t)BATCH * 20 * P_BOX * sizeof(uint32_t);  // 22.35 MB
  if (ws_size >= keys_bytes) {
    uint32_t* keys = (uint32_t*)d_ws;
    int nprep = (NBOX_TOTAL + 255) / 256;
    prep_kernel<<<nprep, 256, 0, stream>>>(loc, conf, priors, keys);
    nms_kernel<true><<<BATCH * NCLS, NTH, 0, stream>>>(loc, conf, priors, keys, out);
  } else {
    nms_kernel<false><<<BATCH * NCLS, NTH, 0, stream>>>(loc, conf, priors, nullptr, out);
  }
}

// Round 5
// 189.752 us; speedup vs baseline: 1.0005x; 1.0005x over previous
//
#include <hip/hip_runtime.h>
#include <cstdint>

#define P_BOX 8732
#define NBOX_TOTAL 279424  // 32*8732
#define BATCH 32
#define NCLS 21
#define NFG 20
#define TOPK 200
#define NTH 256
#define NCH 9  // chunks of 1024 keys; chunk 8 partial (t < 135)
#define CAND_CAP 512
#define NBKT 2048
#define NORM 0xBC23D70Bu  // score_key(0.01f)+1 ; stored keys are pre-normalized
#define LIM (1u << 26)    // normalized key < LIM  <=>  eligible (score > 0.01)
#define CONF_F4 1466976   // 32*8732*21/4

typedef unsigned long long u64;

// monotonic float->u32 (total order), invertible
__device__ __forceinline__ uint32_t score_key(float m) {
  uint32_t b = __float_as_uint(m);
  return (b & 0x80000000u) ? ~b : (b | 0x80000000u);
}
__device__ __forceinline__ float key_score(uint32_t k) {
  uint32_t b = (k & 0x80000000u) ? (k ^ 0x80000000u) : ~k;
  return __uint_as_float(b);
}

// Exactly mirrors reference _decode (fp32).
__device__ __forceinline__ float4 decode_box(const float4 pr, const float4 lc) {
  float px = fmaxf(pr.x, 1e-6f), py = fmaxf(pr.y, 1e-6f);
  float pw = fmaxf(pr.z, 1e-6f), ph = fmaxf(pr.w, 1e-6f);
  float cx = px + lc.x * 0.1f * pw;
  float cy = py + lc.y * 0.1f * ph;
  float lw = fminf(fmaxf(lc.z * 0.2f, -4.0f), 4.0f);
  float lh = fminf(fmaxf(lc.w * 0.2f, -4.0f), 4.0f);
  float w = pw * expf(lw);
  float h = ph * expf(lh);
  float4 r;
  r.x = fminf(fmaxf(cx - 0.5f * w, 0.0f), 1.0f);
  r.y = fminf(fmaxf(cy - 0.5f * h, 0.0f), 1.0f);
  r.z = fminf(fmaxf(cx + 0.5f * w, 0.0f), 1.0f);
  r.w = fminf(fmaxf(cy + 0.5f * h, 0.0f), 1.0f);
  return r;
}

// Prep: 256 boxes/block. Stage conf in LDS; emit normalized masked score-keys,
// class-major: keys[(b*20 + c-1)*P_BOX + p].
__global__ __launch_bounds__(256) void prep_kernel(
    const float* __restrict__ loc, const float* __restrict__ conf,
    const float* __restrict__ priors, uint32_t* __restrict__ keys) {
  __shared__ float s_conf[256 * 21];  // 21504 B
  const int t = threadIdx.x;
  const int blk = blockIdx.x;
  const float4* cf4 = (const float4*)conf;
  size_t base4 = (size_t)blk * 1344;
#pragma unroll
  for (int i = t; i < 1344; i += 256) {
    size_t g4 = base4 + i;
    if (g4 < CONF_F4) ((float4*)s_conf)[i] = cf4[g4];
  }
  __syncthreads();
  int g = blk * 256 + t;
  if (g >= NBOX_TOTAL) return;
  int b = g / P_BOX, p = g - b * P_BOX;
  float x[NCLS];
  float mx = -1e30f;
#pragma unroll
  for (int i = 0; i < NCLS; ++i) {
    float v = fminf(fmaxf(s_conf[t * 21 + i], -100.0f), 100.0f);
    x[i] = v;
    mx = fmaxf(mx, v);
  }
  float s = 0.0f;
#pragma unroll
  for (int i = 0; i < NCLS; ++i) {
    x[i] = expf(x[i] - mx);
    s += x[i];
  }
  float4 bx = decode_box(((const float4*)priors)[p], ((const float4*)loc)[g]);
  bool bok = (bx.z > bx.x + 1e-6f) && (bx.w > bx.y + 1e-6f);
#pragma unroll
  for (int ci = 1; ci < NCLS; ++ci) {
    float sc = x[ci] / s;  // division, matching reference softmax
    float m = (bok && sc > 0.01f) ? sc : -1.0f;
    keys[((size_t)(b * NFG) + (ci - 1)) * P_BOX + p] = score_key(m) - NORM;
  }
}

__device__ __forceinline__ int cnt_ge(const uint32_t* kv, uint32_t X) {
  int n = 0;
#pragma unroll
  for (int j = 0; j < NCH * 4; ++j) n += (kv[j] >= X && kv[j] < LIM) ? 1 : 0;
  return n;
}
__device__ __forceinline__ int cnt_eq_idx(const uint32_t* kv, int t, uint32_t T, uint32_t I) {
  int n = 0;
#pragma unroll
  for (int ch = 0; ch < NCH; ++ch) {
#pragma unroll
    for (int e = 0; e < 4; ++e) {
      int p = ch * 1024 + t * 4 + e;
      n += (kv[ch * 4 + e] == T && (uint32_t)(P_BOX - p) >= I) ? 1 : 0;
    }
  }
  return n;
}

// Block-wide sum, ONE barrier per call (3-slot rotation).
__device__ __forceinline__ int block_count(int v, int t, int* s_cnt, int& it) {
#pragma unroll
  for (int o = 32; o > 0; o >>= 1) v += __shfl_down(v, o, 64);
  int slot = it % 3;
  if (t == 0) s_cnt[(it + 1) % 3] = 0;
  if ((t & 63) == 0) atomicAdd(&s_cnt[slot], v);
  __syncthreads();
  int r = s_cnt[slot];
  ++it;
  return r;
}

// Largest bucket B (of NBKT) with suffix-count >= need; returns
// {B, M=suffix(B), above=suffix(B+1)}. If total < need: {0, total, 0}.
__device__ __forceinline__ int3 select_bucket(const int* s_hist, int* s_S,
                                              int* s_wt, int* s_res, int need,
                                              int t) {
  const int BPT = NBKT / NTH;  // 8
  int base = t * BPT;
  int ps = 0;
#pragma unroll
  for (int i = 0; i < BPT; ++i) ps += s_hist[base + i];
  int l = t & 63, w = t >> 6;
  int v = ps;
#pragma unroll
  for (int off = 1; off < 64; off <<= 1) {
    int o = __shfl_down(v, off, 64);
    v += (l + off < 64) ? o : 0;  // inclusive suffix scan within wave
  }
  if (l == 0) s_wt[w] = v;
  __syncthreads();
  int hi = 0;
#pragma unroll
  for (int w2 = 0; w2 < NTH / 64; ++w2) hi += (w2 > w) ? s_wt[w2] : 0;
  int S = v + hi;  // suffix-count from bucket base = t*BPT
  s_S[t] = S;
  __syncthreads();
  if (t == 0 && s_S[0] < need) {
    s_res[0] = 0; s_res[1] = s_S[0]; s_res[2] = 0;
  } else if (s_S[t] >= need && (t == NTH - 1 || s_S[t + 1] < need)) {
    int suf = (t == NTH - 1) ? 0 : s_S[t + 1];
    int B = base, M = 0;
    for (int j = base + BPT - 1; j >= base; --j) {
      suf += s_hist[j];
      if (suf >= need) { B = j; M = suf; break; }
    }
    s_res[0] = B; s_res[1] = M; s_res[2] = M - s_hist[B];
  }
  __syncthreads();
  return make_int3(s_res[0], s_res[1], s_res[2]);
}

// ---------- Kernel A: per-fg-task top-200 selection -> ws ----------
// grid = 640 (b*20 + c-1). Writes g_sel[ft*200 + rank] (ordered) and g_nsel[ft].
__global__ __launch_bounds__(256) void select_kernel(
    const uint32_t* __restrict__ keys, u64* __restrict__ g_sel,
    int* __restrict__ g_nsel) {
  const int t = threadIdx.x;
  const int ft = blockIdx.x;  // == key row index

  __shared__ alignas(16) int s_hist[NBKT];      // 8 KB
  __shared__ alignas(16) u64 s_cand[CAND_CAP];  // 4 KB; aliased by s_S
  __shared__ int s_wt[NTH / 64];
  __shared__ int s_res[3];
  __shared__ int s_cnt[3];
  __shared__ int s_m;
  int* s_S = (int*)s_cand;

  if (t == 0) { s_cnt[0] = 0; s_cnt[1] = 0; s_cnt[2] = 0; s_m = 0; }
  for (int i = t; i < NBKT; i += NTH) s_hist[i] = 0;

  // ---- load this task's 8732 normalized keys into registers (36/thread) ----
  uint32_t kv[NCH * 4];
  {
    const uint4* kp = (const uint4*)(keys + (size_t)ft * P_BOX);
#pragma unroll
    for (int ch = 0; ch < 8; ++ch) {
      uint4 v = kp[ch * 256 + t];
      kv[ch * 4 + 0] = v.x; kv[ch * 4 + 1] = v.y;
      kv[ch * 4 + 2] = v.z; kv[ch * 4 + 3] = v.w;
    }
    if (t < 135) {
      uint4 v = kp[2048 + t];
      kv[32] = v.x; kv[33] = v.y; kv[34] = v.z; kv[35] = v.w;
    } else {
      kv[32] = LIM; kv[33] = LIM; kv[34] = LIM; kv[35] = LIM;
    }
  }
  __syncthreads();

  // ---- 2048-bucket histogram of key bits [25:15] ----
#pragma unroll
  for (int j = 0; j < NCH * 4; ++j)
    if (kv[j] < LIM) atomicAdd(&s_hist[kv[j] >> 15], 1);
  __syncthreads();
  int3 r1 = select_bucket(s_hist, s_S, s_wt, s_res, TOPK, t);
  uint32_t Tp = (uint32_t)r1.x << 15;
  int M = r1.y;
  bool ex = false;
  uint32_t Tex = 0, I = 0;

  if (M > CAND_CAP) {  // rare: refine within bucket (width-16 sub-buckets)
    uint32_t B1 = (uint32_t)r1.x;
    int above1 = r1.z;
    __syncthreads();
    for (int i = t; i < NBKT; i += NTH) s_hist[i] = 0;
    __syncthreads();
#pragma unroll
    for (int j = 0; j < NCH * 4; ++j)
      if (kv[j] < LIM && (kv[j] >> 15) == B1)
        atomicAdd(&s_hist[(kv[j] >> 4) & (NBKT - 1)], 1);
    __syncthreads();
    int3 r2 = select_bucket(s_hist, s_S, s_wt, s_res, TOPK - above1, t);
    Tp = (B1 << 15) + ((uint32_t)r2.x << 4);
    M = above1 + r2.y;
    if (M > CAND_CAP) {  // pathological ties: exact key + index refinement
      int it = 0;
      uint32_t lo = Tp, hi = LIM;
      while (hi - lo > 1) {
        uint32_t mid = lo + ((hi - lo) >> 1);
        int cnt = block_count(cnt_ge(kv, mid), t, s_cnt, it);
        if (cnt >= TOPK) lo = mid; else hi = mid;
      }
      Tex = lo;
      int G = block_count(cnt_ge(kv, Tex + 1), t, s_cnt, it);
      int R = TOPK - G;  // >= 1
      uint32_t lo2 = 1, hi2 = P_BOX + 1;
      while (hi2 - lo2 > 1) {
        uint32_t mid = lo2 + ((hi2 - lo2) >> 1);
        int cnt = block_count(cnt_eq_idx(kv, t, Tex, mid), t, s_cnt, it);
        if (cnt >= R) lo2 = mid; else hi2 = mid;
      }
      I = lo2;
      ex = true;  // M becomes exactly 200 at gather
    }
  }
  __syncthreads();  // s_S (alias s_cand) dead; safe to gather

  // ---- gather candidates (packed key|P-p for exact total order) ----
#pragma unroll
  for (int ch = 0; ch < NCH; ++ch) {
#pragma unroll
    for (int e = 0; e < 4; ++e) {
      uint32_t k = kv[ch * 4 + e];
      if (k < LIM) {
        int p = ch * 1024 + 4 * t + e;
        bool take = ex ? (k > Tex || (k == Tex && (uint32_t)(P_BOX - p) >= I))
                       : (k >= Tp);
        if (take) {
          int ix = atomicAdd(&s_m, 1);
          if (ix < CAND_CAP) s_cand[ix] = ((u64)k << 32) | (uint32_t)(P_BOX - p);
        }
      }
    }
  }
  __syncthreads();
  M = min(s_m, CAND_CAP);
  int nsel = min(M, TOPK);
  if (t == 0) g_nsel[ft] = nsel;

  // ---- rank (exact order; ties by smaller p) -> write DIRECT to global ----
  for (int ci = t; ci < M; ci += NTH) {
    u64 mine = s_cand[ci];
    int r = 0;
    int j = 0;
    for (; j + 8 <= M; j += 8) {  // 8 independent LDS loads per group
      u64 a0 = s_cand[j + 0], a1 = s_cand[j + 1], a2 = s_cand[j + 2],
          a3 = s_cand[j + 3], a4 = s_cand[j + 4], a5 = s_cand[j + 5],
          a6 = s_cand[j + 6], a7 = s_cand[j + 7];
      r += (a0 > mine) + (a1 > mine) + (a2 > mine) + (a3 > mine) +
           (a4 > mine) + (a5 > mine) + (a6 > mine) + (a7 > mine);
    }
    for (; j < M; ++j) r += (s_cand[j] > mine) ? 1 : 0;
    if (r < TOPK) g_sel[(size_t)ft * TOPK + r] = mine;
  }
}

// ---------- Kernel B: per-task NMS + output ----------
// grid = 672 (b*21 + c). Reads g_sel/g_nsel, writes out rows.
__global__ __launch_bounds__(256) void nms2_kernel(
    const float* __restrict__ loc, const float* __restrict__ priors,
    const u64* __restrict__ g_sel, const int* __restrict__ g_nsel,
    float* __restrict__ out) {
  const int t = threadIdx.x;
  const int task = blockIdx.x;
  const int b = task / NCLS, c = task - b * NCLS;
  float* ob = out + (size_t)task * TOPK * 5;

  if (c == 0) {  // background class: all-zero rows
    float4 z = make_float4(0.f, 0.f, 0.f, 0.f);
    for (int i = t; i < TOPK * 5 / 4; i += NTH) ((float4*)ob)[i] = z;
    return;
  }
  const int ft = b * NFG + (c - 1);
  const int nsel = g_nsel[ft];

  __shared__ alignas(16) u64 s_sup[TOPK * 4];  // 6.4 KB; aliased by s_rows
  __shared__ float4 s_box[256];
  __shared__ float s_area[256];
  __shared__ float s_score[256];
  __shared__ u64 s_alive[4];
  __shared__ short s_kept[TOPK];
  float* s_rows = (float*)s_sup;  // 1000 floats, epilogue staging

  // ---- load selected, decode boxes ----
  if (t < nsel) {
    u64 w = g_sel[(size_t)ft * TOPK + t];
    uint32_t k = (uint32_t)(w >> 32);
    int p = P_BOX - (int)(uint32_t)(w & 0xFFFFFFFFull);
    float4 bx = decode_box(((const float4*)priors)[p],
                           ((const float4*)loc)[(size_t)b * P_BOX + p]);
    s_box[t] = bx;
    s_area[t] = (bx.z - bx.x) * (bx.w - bx.y);
    s_score[t] = key_score(k + NORM);
  } else {
    s_box[t] = make_float4(0.f, 0.f, 0.f, 0.f);
    s_area[t] = 0.f;
    s_score[t] = 0.f;
  }
  for (int i = t; i < TOPK * 4; i += NTH) s_sup[i] = 0ull;
  __syncthreads();

  // ---- suppression bitmasks via ballot (4 waves, row-strided, prefetched) ----
  {
    int wv = t >> 6, l = t & 63;
    float4 bj[4];
    float aj[4];
#pragma unroll
    for (int cc = 0; cc < 4; ++cc) {
      bj[cc] = s_box[cc * 64 + l];
      aj[cc] = s_area[cc * 64 + l];
    }
    int cmax = (nsel + 63) >> 6;
    float4 bi;
    float ai;
    if (wv < nsel) { bi = s_box[wv]; ai = s_area[wv]; }
    for (int i = wv; i < nsel; i += 4) {
      int in_ = i + 4;
      float4 bn = bi;
      float an = ai;
      if (in_ < nsel) { bn = s_box[in_]; an = s_area[in_]; }  // prefetch next row
      int c0 = i >> 6;
      for (int cc = c0; cc < cmax; ++cc) {
        int j = cc * 64 + l;
        float lx = fmaxf(bi.x, bj[cc].x), ly = fmaxf(bi.y, bj[cc].y);
        float rx = fminf(bi.z, bj[cc].z), ry = fminf(bi.w, bj[cc].w);
        float iw = fmaxf(rx - lx, 0.0f), ih = fmaxf(ry - ly, 0.0f);
        float inter = iw * ih;
        float uni = ai + aj[cc] - inter;
        float iou = inter / fmaxf(uni, 1e-12f);
        bool sup = (j > i) && (j < nsel) && (iou > 0.45f);
        u64 m = __ballot(sup);
        if (l == 0) s_sup[i * 4 + cc] = m;
      }
      bi = bn;
      ai = an;
    }
  }
  __syncthreads();

  // ---- serial greedy walk, software-pipelined row prefetch ----
  if (t == 0) {
    u64 aw0, aw1, aw2, aw3;
    {
      int r0 = nsel, r1 = nsel - 64, r2 = nsel - 128, r3 = nsel - 192;
      aw0 = r0 >= 64 ? ~0ull : (r0 <= 0 ? 0ull : ((1ull << r0) - 1));
      aw1 = r1 >= 64 ? ~0ull : (r1 <= 0 ? 0ull : ((1ull << r1) - 1));
      aw2 = r2 >= 64 ? ~0ull : (r2 <= 0 ? 0ull : ((1ull << r2) - 1));
      aw3 = r3 >= 64 ? ~0ull : (r3 <= 0 ? 0ull : ((1ull << r3) - 1));
    }
    u64 p0 = s_sup[0], p1 = s_sup[1], p2 = s_sup[2], p3 = s_sup[3];
    for (int i = 0; i < nsel; ++i) {
      u64 c0 = p0, c1 = p1, c2 = p2, c3 = p3;
      int j = i + 1;
      if (j < nsel) {
        p0 = s_sup[j * 4 + 0]; p1 = s_sup[j * 4 + 1];
        p2 = s_sup[j * 4 + 2]; p3 = s_sup[j * 4 + 3];
      }
      int w = i >> 6;
      u64 cur = (w == 0) ? aw0 : (w == 1) ? aw1 : (w == 2) ? aw2 : aw3;
      if ((cur >> (i & 63)) & 1ull) {
        aw0 &= ~c0; aw1 &= ~c1; aw2 &= ~c2; aw3 &= ~c3;
      }
    }
    s_alive[0] = aw0; s_alive[1] = aw1; s_alive[2] = aw2; s_alive[3] = aw3;
  }
  __syncthreads();

  // ---- compact kept to front via popcount ranks ----
  u64 w0 = s_alive[0], w1 = s_alive[1], w2 = s_alive[2], w3 = s_alive[3];
  int pc0 = __popcll(w0), pc01 = pc0 + __popcll(w1), pc012 = pc01 + __popcll(w2);
  int nk = pc012 + __popcll(w3);
  if (t < nsel) {
    int word = t >> 6, bit = t & 63;
    u64 wt = (word == 0) ? w0 : (word == 1) ? w1 : (word == 2) ? w2 : w3;
    if ((wt >> bit) & 1ull) {
      int base = (word == 0) ? 0 : (word == 1) ? pc0 : (word == 2) ? pc01 : pc012;
      int r = base + __popcll(wt & ((1ull << bit) - 1ull));
      s_kept[r] = (short)t;
    }
  }
  __syncthreads();

  // ---- stage rows in LDS (aliases s_sup, now dead), coalesced store ----
  if (t < TOPK) {
    float r0 = 0.f, r1 = 0.f, r2 = 0.f, r3 = 0.f, r4 = 0.f;
    if (t < nk) {
      int j = s_kept[t];
      r0 = s_score[j];
      float4 bx = s_box[j];
      r1 = bx.x; r2 = bx.y; r3 = bx.z; r4 = bx.w;
    }
    s_rows[t * 5 + 0] = r0; s_rows[t * 5 + 1] = r1; s_rows[t * 5 + 2] = r2;
    s_rows[t * 5 + 3] = r3; s_rows[t * 5 + 4] = r4;
  }
  __syncthreads();
  for (int i = t; i < TOPK * 5 / 4; i += NTH)
    ((float4*)ob)[i] = ((float4*)s_rows)[i];
}

// ---------- Fallback: fully fused (recompute) — only if ws is too small ----------
__global__ __launch_bounds__(256) void nms_fused_kernel(
    const float* __restrict__ loc, const float* __restrict__ conf,
    const float* __restrict__ priors, float* __restrict__ out) {
  const int t = threadIdx.x;
  const int task = blockIdx.x;
  const int b = task / NCLS, c = task - b * NCLS;
  float* ob = out + (size_t)task * TOPK * 5;
  if (c == 0) {
    float4 z = make_float4(0.f, 0.f, 0.f, 0.f);
    for (int i = t; i < TOPK * 5 / 4; i += NTH) ((float4*)ob)[i] = z;
    return;
  }
  __shared__ alignas(16) int s_hist[NBKT];
  __shared__ alignas(16) u64 s_cand[CAND_CAP];
  __shared__ u64 s_sel[TOPK];
  __shared__ float4 s_box[256];
  __shared__ float s_area[256];
  __shared__ float s_score[256];
  __shared__ u64 s_alive[4];
  __shared__ short s_kept[TOPK];
  __shared__ int s_wt[NTH / 64];
  __shared__ int s_res[3];
  __shared__ int s_cnt[3];
  __shared__ int s_m;
  u64* s_sup = (u64*)s_hist;
  int* s_S = (int*)s_cand;
  float* s_rows = (float*)s_cand;

  if (t == 0) { s_cnt[0] = 0; s_cnt[1] = 0; s_cnt[2] = 0; s_m = 0; }
  for (int i = t; i < NBKT; i += NTH) s_hist[i] = 0;

  uint32_t kv[NCH * 4];
  for (int ch = 0; ch < NCH; ++ch) {
    int p0 = ch * 1024 + 4 * t;
#pragma unroll
    for (int e = 0; e < 4; ++e) {
      int p = p0 + e;
      uint32_t k = LIM;
      if (p < P_BOX) {
        const float* cf = conf + (size_t)(b * P_BOX + p) * NCLS;
        float x[NCLS];
        float mx = -1e30f;
#pragma unroll
        for (int i = 0; i < NCLS; ++i) {
          float v = fminf(fmaxf(cf[i], -100.0f), 100.0f);
          x[i] = v;
          mx = fmaxf(mx, v);
        }
        float ssum = 0.0f, ec = 0.0f;
#pragma unroll
        for (int i = 0; i < NCLS; ++i) {
          float ex = expf(x[i] - mx);
          ssum += ex;
          if (i == c) ec = ex;
        }
        float sc = ec / ssum;
        float4 bx = decode_box(((const float4*)priors)[p],
                               ((const float4*)loc)[(size_t)b * P_BOX + p]);
        bool valid = (sc > 0.01f) && (bx.z > bx.x + 1e-6f) && (bx.w > bx.y + 1e-6f);
        k = score_key(valid ? sc : -1.0f) - NORM;
      }
      kv[ch * 4 + e] = k;
    }
  }
  __syncthreads();
#pragma unroll
  for (int j = 0; j < NCH * 4; ++j)
    if (kv[j] < LIM) atomicAdd(&s_hist[kv[j] >> 15], 1);
  __syncthreads();
  int3 r1 = select_bucket(s_hist, s_S, s_wt, s_res, TOPK, t);
  uint32_t Tp = (uint32_t)r1.x << 15;
  int M = r1.y;
  bool ex = false;
  uint32_t Tex = 0, I = 0;
  if (M > CAND_CAP) {
    uint32_t B1 = (uint32_t)r1.x;
    int above1 = r1.z;
    __syncthreads();
    for (int i = t; i < NBKT; i += NTH) s_hist[i] = 0;
    __syncthreads();
#pragma unroll
    for (int j = 0; j < NCH * 4; ++j)
      if (kv[j] < LIM && (kv[j] >> 15) == B1)
        atomicAdd(&s_hist[(kv[j] >> 4) & (NBKT - 1)], 1);
    __syncthreads();
    int3 r2 = select_bucket(s_hist, s_S, s_wt, s_res, TOPK - above1, t);
    Tp = (B1 << 15) + ((uint32_t)r2.x << 4);
    M = above1 + r2.y;
    if (M > CAND_CAP) {
      int it = 0;
      uint32_t lo = Tp, hi = LIM;
      while (hi - lo > 1) {
        uint32_t mid = lo + ((hi - lo) >> 1);
        int cnt = block_count(cnt_ge(kv, mid), t, s_cnt, it);
        if (cnt >= TOPK) lo = mid; else hi = mid;
      }
      Tex = lo;
      int G = block_count(cnt_ge(kv, Tex + 1), t, s_cnt, it);
      int R = TOPK - G;
      uint32_t lo2 = 1, hi2 = P_BOX + 1;
      while (hi2 - lo2 > 1) {
        uint32_t mid = lo2 + ((hi2 - lo2) >> 1);
        int cnt = block_count(cnt_eq_idx(kv, t, Tex, mid), t, s_cnt, it);
        if (cnt >= R) lo2 = mid; else hi2 = mid;
      }
      I = lo2;
      ex = true;
    }
  }
  __syncthreads();
#pragma unroll
  for (int ch = 0; ch < NCH; ++ch) {
#pragma unroll
    for (int e = 0; e < 4; ++e) {
      uint32_t k = kv[ch * 4 + e];
      if (k < LIM) {
        int p = ch * 1024 + 4 * t + e;
        bool take = ex ? (k > Tex || (k == Tex && (uint32_t)(P_BOX - p) >= I))
                       : (k >= Tp);
        if (take) {
          int ix = atomicAdd(&s_m, 1);
          if (ix < CAND_CAP) s_cand[ix] = ((u64)k << 32) | (uint32_t)(P_BOX - p);
        }
      }
    }
  }
  __syncthreads();
  M = min(s_m, CAND_CAP);
  int nsel = min(M, TOPK);
  for (int ci = t; ci < M; ci += NTH) {
    u64 mine = s_cand[ci];
    int r = 0;
    for (int j = 0; j < M; ++j) r += (s_cand[j] > mine) ? 1 : 0;
    if (r < TOPK) s_sel[r] = mine;
  }
  __syncthreads();
  if (t < nsel) {
    u64 w = s_sel[t];
    uint32_t k = (uint32_t)(w >> 32);
    int p = P_BOX - (int)(uint32_t)(w & 0xFFFFFFFFull);
    float4 bx = decode_box(((const float4*)priors)[p],
                           ((const float4*)loc)[(size_t)b * P_BOX + p]);
    s_box[t] = bx;
    s_area[t] = (bx.z - bx.x) * (bx.w - bx.y);
    s_score[t] = key_score(k + NORM);
  } else {
    s_box[t] = make_float4(0.f, 0.f, 0.f, 0.f);
    s_area[t] = 0.f;
    s_score[t] = 0.f;
  }
  for (int i = t; i < TOPK * 4; i += NTH) s_sup[i] = 0ull;
  __syncthreads();
  {
    int wv = t >> 6, l = t & 63;
    float4 bj[4];
    float aj[4];
#pragma unroll
    for (int cc = 0; cc < 4; ++cc) {
      bj[cc] = s_box[cc * 64 + l];
      aj[cc] = s_area[cc * 64 + l];
    }
    int cmax = (nsel + 63) >> 6;
    for (int i = wv; i < nsel; i += 4) {
      float4 bi = s_box[i];
      float ai = s_area[i];
      int c0 = i >> 6;
      for (int cc = c0; cc < cmax; ++cc) {
        int j = cc * 64 + l;
        float lx = fmaxf(bi.x, bj[cc].x), ly = fmaxf(bi.y, bj[cc].y);
        float rx = fminf(bi.z, bj[cc].z), ry = fminf(bi.w, bj[cc].w);
        float iw = fmaxf(rx - lx, 0.0f), ih = fmaxf(ry - ly, 0.0f);
        float inter = iw * ih;
        float uni = ai + aj[cc] - inter;
        float iou = inter / fmaxf(uni, 1e-12f);
        bool sup = (j > i) && (j < nsel) && (iou > 0.45f);
        u64 m = __ballot(sup);
        if (l == 0) s_sup[i * 4 + cc] = m;
      }
    }
  }
  __syncthreads();
  if (t == 0) {
    u64 aw0, aw1, aw2, aw3;
    int r0 = nsel, r1b = nsel - 64, r2b = nsel - 128, r3b = nsel - 192;
    aw0 = r0 >= 64 ? ~0ull : (r0 <= 0 ? 0ull : ((1ull << r0) - 1));
    aw1 = r1b >= 64 ? ~0ull : (r1b <= 0 ? 0ull : ((1ull << r1b) - 1));
    aw2 = r2b >= 64 ? ~0ull : (r2b <= 0 ? 0ull : ((1ull << r2b) - 1));
    aw3 = r3b >= 64 ? ~0ull : (r3b <= 0 ? 0ull : ((1ull << r3b) - 1));
    for (int i = 0; i < nsel; ++i) {
      int w = i >> 6;
      u64 cur = (w == 0) ? aw0 : (w == 1) ? aw1 : (w == 2) ? aw2 : aw3;
      if ((cur >> (i & 63)) & 1ull) {
        aw0 &= ~s_sup[i * 4 + 0]; aw1 &= ~s_sup[i * 4 + 1];
        aw2 &= ~s_sup[i * 4 + 2]; aw3 &= ~s_sup[i * 4 + 3];
      }
    }
    s_alive[0] = aw0; s_alive[1] = aw1; s_alive[2] = aw2; s_alive[3] = aw3;
  }
  __syncthreads();
  u64 w0 = s_alive[0], w1 = s_alive[1], w2 = s_alive[2], w3 = s_alive[3];
  int pc0 = __popcll(w0), pc01 = pc0 + __popcll(w1), pc012 = pc01 + __popcll(w2);
  int nk = pc012 + __popcll(w3);
  if (t < nsel) {
    int word = t >> 6, bit = t & 63;
    u64 wt = (word == 0) ? w0 : (word == 1) ? w1 : (word == 2) ? w2 : w3;
    if ((wt >> bit) & 1ull) {
      int base = (word == 0) ? 0 : (word == 1) ? pc0 : (word == 2) ? pc01 : pc012;
      int r = base + __popcll(wt & ((1ull << bit) - 1ull));
      s_kept[r] = (short)t;
    }
  }
  __syncthreads();
  if (t < TOPK) {
    float r0 = 0.f, r1b = 0.f, r2b = 0.f, r3b = 0.f, r4 = 0.f;
    if (t < nk) {
      int j = s_kept[t];
      r0 = s_score[j];
      float4 bx = s_box[j];
      r1b = bx.x; r2b = bx.y; r3b = bx.z; r4 = bx.w;
    }
    s_rows[t * 5 + 0] = r0; s_rows[t * 5 + 1] = r1b; s_rows[t * 5 + 2] = r2b;
    s_rows[t * 5 + 3] = r3b; s_rows[t * 5 + 4] = r4;
  }
  __syncthreads();
  for (int i = t; i < TOPK * 5 / 4; i += NTH)
    ((float4*)ob)[i] = ((float4*)s_rows)[i];
}

extern "C" void kernel_launch(void* const* d_in, const int* in_sizes, int n_in,
                              void* d_out, int out_size, void* d_ws, size_t ws_size,
                              hipStream_t stream) {
  (void)in_sizes;
  (void)n_in;
  (void)out_size;
  const float* loc = (const float*)d_in[0];     // [B,P,4]
  const float* conf = (const float*)d_in[1];    // [B,P,21]
  const float* priors = (const float*)d_in[2];  // [P,4]
  float* out = (float*)d_out;                   // [B,21,200,5]

  size_t keys_bytes = (size_t)BATCH * NFG * P_BOX * sizeof(uint32_t);  // 22.35 MB
  size_t sel_bytes = (size_t)BATCH * NFG * TOPK * sizeof(u64);         // 1.02 MB
  size_t nsel_bytes = (size_t)BATCH * NFG * sizeof(int);
  if (ws_size >= keys_bytes + sel_bytes + nsel_bytes) {
    uint32_t* keys = (uint32_t*)d_ws;
    u64* g_sel = (u64*)((char*)d_ws + keys_bytes);
    int* g_nsel = (int*)((char*)d_ws + keys_bytes + sel_bytes);
    int nprep = (NBOX_TOTAL + 255) / 256;
    prep_kernel<<<nprep, 256, 0, stream>>>(loc, conf, priors, keys);
    select_kernel<<<BATCH * NFG, NTH, 0, stream>>>(keys, g_sel, g_nsel);
    nms2_kernel<<<BATCH * NCLS, NTH, 0, stream>>>(loc, priors, g_sel, g_nsel, out);
  } else {
    nms_fused_kernel<<<BATCH * NCLS, NTH, 0, stream>>>(loc, conf, priors, out);
  }
}

// Round 6
// 172.450 us; speedup vs baseline: 1.1009x; 1.1003x over previous
//
#include <hip/hip_runtime.h>
#include <cstdint>

#define P_BOX 8732
#define NBOX_TOTAL 279424  // 32*8732
#define BATCH 32
#define NCLS 21
#define NFG 20
#define TOPK 200
#define NTH 256
#define NCH 9  // chunks of 1024 keys; chunk 8 partial (t < 135)
#define CAND_CAP 512
#define NBKT 2048
#define NORM 0xBC23D70Bu  // score_key(0.01f)+1 ; stored keys are pre-normalized
#define LIM (1u << 26)    // normalized key < LIM  <=>  eligible (score > 0.01)
#define CONF_F4 1466976   // 32*8732*21/4

typedef unsigned long long u64;

__device__ __forceinline__ uint32_t score_key(float m) {
  uint32_t b = __float_as_uint(m);
  return (b & 0x80000000u) ? ~b : (b | 0x80000000u);
}
__device__ __forceinline__ float key_score(uint32_t k) {
  uint32_t b = (k & 0x80000000u) ? (k ^ 0x80000000u) : ~k;
  return __uint_as_float(b);
}

__device__ __forceinline__ u64 shfl_down_u64(u64 v, int off) {
  int lo = (int)(uint32_t)(v & 0xFFFFFFFFull);
  int hi = (int)(uint32_t)(v >> 32);
  lo = __shfl_down(lo, off, 64);
  hi = __shfl_down(hi, off, 64);
  return ((u64)(uint32_t)hi << 32) | (uint32_t)lo;
}

// Exactly mirrors reference _decode (fp32).
__device__ __forceinline__ float4 decode_box(const float4 pr, const float4 lc) {
  float px = fmaxf(pr.x, 1e-6f), py = fmaxf(pr.y, 1e-6f);
  float pw = fmaxf(pr.z, 1e-6f), ph = fmaxf(pr.w, 1e-6f);
  float cx = px + lc.x * 0.1f * pw;
  float cy = py + lc.y * 0.1f * ph;
  float lw = fminf(fmaxf(lc.z * 0.2f, -4.0f), 4.0f);
  float lh = fminf(fmaxf(lc.w * 0.2f, -4.0f), 4.0f);
  float w = pw * expf(lw);
  float h = ph * expf(lh);
  float4 r;
  r.x = fminf(fmaxf(cx - 0.5f * w, 0.0f), 1.0f);
  r.y = fminf(fmaxf(cy - 0.5f * h, 0.0f), 1.0f);
  r.z = fminf(fmaxf(cx + 0.5f * w, 0.0f), 1.0f);
  r.w = fminf(fmaxf(cy + 0.5f * h, 0.0f), 1.0f);
  return r;
}

// Prep: 256 boxes/block. Stage conf in LDS; emit normalized masked score-keys,
// class-major: keys[(b*20 + c-1)*P_BOX + p].
__global__ __launch_bounds__(256) void prep_kernel(
    const float* __restrict__ loc, const float* __restrict__ conf,
    const float* __restrict__ priors, uint32_t* __restrict__ keys) {
  __shared__ float s_conf[256 * 21];
  const int t = threadIdx.x;
  const int blk = blockIdx.x;
  const float4* cf4 = (const float4*)conf;
  size_t base4 = (size_t)blk * 1344;
#pragma unroll
  for (int i = t; i < 1344; i += 256) {
    size_t g4 = base4 + i;
    if (g4 < CONF_F4) ((float4*)s_conf)[i] = cf4[g4];
  }
  __syncthreads();
  int g = blk * 256 + t;
  if (g >= NBOX_TOTAL) return;
  int b = g / P_BOX, p = g - b * P_BOX;
  float x[NCLS];
  float mx = -1e30f;
#pragma unroll
  for (int i = 0; i < NCLS; ++i) {
    float v = fminf(fmaxf(s_conf[t * 21 + i], -100.0f), 100.0f);
    x[i] = v;
    mx = fmaxf(mx, v);
  }
  float s = 0.0f;
#pragma unroll
  for (int i = 0; i < NCLS; ++i) {
    x[i] = expf(x[i] - mx);
    s += x[i];
  }
  float4 bx = decode_box(((const float4*)priors)[p], ((const float4*)loc)[g]);
  bool bok = (bx.z > bx.x + 1e-6f) && (bx.w > bx.y + 1e-6f);
#pragma unroll
  for (int ci = 1; ci < NCLS; ++ci) {
    float sc = x[ci] / s;
    float m = (bok && sc > 0.01f) ? sc : -1.0f;
    keys[((size_t)(b * NFG) + (ci - 1)) * P_BOX + p] = score_key(m) - NORM;
  }
}

__device__ __forceinline__ int cnt_ge(const uint32_t* kv, uint32_t X) {
  int n = 0;
#pragma unroll
  for (int j = 0; j < NCH * 4; ++j) n += (kv[j] >= X && kv[j] < LIM) ? 1 : 0;
  return n;
}
__device__ __forceinline__ int cnt_eq_idx(const uint32_t* kv, int t, uint32_t T, uint32_t I) {
  int n = 0;
#pragma unroll
  for (int ch = 0; ch < NCH; ++ch) {
#pragma unroll
    for (int e = 0; e < 4; ++e) {
      int p = ch * 1024 + t * 4 + e;
      n += (kv[ch * 4 + e] == T && (uint32_t)(P_BOX - p) >= I) ? 1 : 0;
    }
  }
  return n;
}

__device__ __forceinline__ int block_count(int v, int t, int* s_cnt, int& it) {
#pragma unroll
  for (int o = 32; o > 0; o >>= 1) v += __shfl_down(v, o, 64);
  int slot = it % 3;
  if (t == 0) s_cnt[(it + 1) % 3] = 0;
  if ((t & 63) == 0) atomicAdd(&s_cnt[slot], v);
  __syncthreads();
  int r = s_cnt[slot];
  ++it;
  return r;
}

__device__ __forceinline__ int3 select_bucket(const int* s_hist, int* s_S,
                                              int* s_wt, int* s_res, int need,
                                              int t) {
  const int BPT = NBKT / NTH;  // 8
  int base = t * BPT;
  int ps = 0;
#pragma unroll
  for (int i = 0; i < BPT; ++i) ps += s_hist[base + i];
  int l = t & 63, w = t >> 6;
  int v = ps;
#pragma unroll
  for (int off = 1; off < 64; off <<= 1) {
    int o = __shfl_down(v, off, 64);
    v += (l + off < 64) ? o : 0;
  }
  if (l == 0) s_wt[w] = v;
  __syncthreads();
  int hi = 0;
#pragma unroll
  for (int w2 = 0; w2 < NTH / 64; ++w2) hi += (w2 > w) ? s_wt[w2] : 0;
  int S = v + hi;
  s_S[t] = S;
  __syncthreads();
  if (t == 0 && s_S[0] < need) {
    s_res[0] = 0; s_res[1] = s_S[0]; s_res[2] = 0;
  } else if (s_S[t] >= need && (t == NTH - 1 || s_S[t + 1] < need)) {
    int suf = (t == NTH - 1) ? 0 : s_S[t + 1];
    int B = base, M = 0;
    for (int j = base + BPT - 1; j >= base; --j) {
      suf += s_hist[j];
      if (suf >= need) { B = j; M = suf; break; }
    }
    s_res[0] = B; s_res[1] = M; s_res[2] = M - s_hist[B];
  }
  __syncthreads();
  return make_int3(s_res[0], s_res[1], s_res[2]);
}

// ---------- Kernel A: per-fg-task top-200 selection -> ws ----------
__global__ __launch_bounds__(256) void select_kernel(
    const uint32_t* __restrict__ keys, u64* __restrict__ g_sel,
    int* __restrict__ g_nsel) {
  const int t = threadIdx.x;
  const int ft = blockIdx.x;

  __shared__ alignas(16) int s_hist[NBKT];
  __shared__ alignas(16) u64 s_cand[CAND_CAP];
  __shared__ int s_wt[NTH / 64];
  __shared__ int s_res[3];
  __shared__ int s_cnt[3];
  __shared__ int s_m;
  int* s_S = (int*)s_cand;

  if (t == 0) { s_cnt[0] = 0; s_cnt[1] = 0; s_cnt[2] = 0; s_m = 0; }
  for (int i = t; i < NBKT; i += NTH) s_hist[i] = 0;

  uint32_t kv[NCH * 4];
  {
    const uint4* kp = (const uint4*)(keys + (size_t)ft * P_BOX);
#pragma unroll
    for (int ch = 0; ch < 8; ++ch) {
      uint4 v = kp[ch * 256 + t];
      kv[ch * 4 + 0] = v.x; kv[ch * 4 + 1] = v.y;
      kv[ch * 4 + 2] = v.z; kv[ch * 4 + 3] = v.w;
    }
    if (t < 135) {
      uint4 v = kp[2048 + t];
      kv[32] = v.x; kv[33] = v.y; kv[34] = v.z; kv[35] = v.w;
    } else {
      kv[32] = LIM; kv[33] = LIM; kv[34] = LIM; kv[35] = LIM;
    }
  }
  __syncthreads();

#pragma unroll
  for (int j = 0; j < NCH * 4; ++j)
    if (kv[j] < LIM) atomicAdd(&s_hist[kv[j] >> 15], 1);
  __syncthreads();
  int3 r1 = select_bucket(s_hist, s_S, s_wt, s_res, TOPK, t);
  uint32_t Tp = (uint32_t)r1.x << 15;
  int M = r1.y;
  bool ex = false;
  uint32_t Tex = 0, I = 0;

  if (M > CAND_CAP) {
    uint32_t B1 = (uint32_t)r1.x;
    int above1 = r1.z;
    __syncthreads();
    for (int i = t; i < NBKT; i += NTH) s_hist[i] = 0;
    __syncthreads();
#pragma unroll
    for (int j = 0; j < NCH * 4; ++j)
      if (kv[j] < LIM && (kv[j] >> 15) == B1)
        atomicAdd(&s_hist[(kv[j] >> 4) & (NBKT - 1)], 1);
    __syncthreads();
    int3 r2 = select_bucket(s_hist, s_S, s_wt, s_res, TOPK - above1, t);
    Tp = (B1 << 15) + ((uint32_t)r2.x << 4);
    M = above1 + r2.y;
    if (M > CAND_CAP) {
      int it = 0;
      uint32_t lo = Tp, hi = LIM;
      while (hi - lo > 1) {
        uint32_t mid = lo + ((hi - lo) >> 1);
        int cnt = block_count(cnt_ge(kv, mid), t, s_cnt, it);
        if (cnt >= TOPK) lo = mid; else hi = mid;
      }
      Tex = lo;
      int G = block_count(cnt_ge(kv, Tex + 1), t, s_cnt, it);
      int R = TOPK - G;
      uint32_t lo2 = 1, hi2 = P_BOX + 1;
      while (hi2 - lo2 > 1) {
        uint32_t mid = lo2 + ((hi2 - lo2) >> 1);
        int cnt = block_count(cnt_eq_idx(kv, t, Tex, mid), t, s_cnt, it);
        if (cnt >= R) lo2 = mid; else hi2 = mid;
      }
      I = lo2;
      ex = true;
    }
  }
  __syncthreads();

#pragma unroll
  for (int ch = 0; ch < NCH; ++ch) {
#pragma unroll
    for (int e = 0; e < 4; ++e) {
      uint32_t k = kv[ch * 4 + e];
      if (k < LIM) {
        int p = ch * 1024 + 4 * t + e;
        bool take = ex ? (k > Tex || (k == Tex && (uint32_t)(P_BOX - p) >= I))
                       : (k >= Tp);
        if (take) {
          int ix = atomicAdd(&s_m, 1);
          if (ix < CAND_CAP) s_cand[ix] = ((u64)k << 32) | (uint32_t)(P_BOX - p);
        }
      }
    }
  }
  __syncthreads();
  M = min(s_m, CAND_CAP);
  int nsel = min(M, TOPK);
  if (t == 0) g_nsel[ft] = nsel;

  for (int ci = t; ci < M; ci += NTH) {
    u64 mine = s_cand[ci];
    int r = 0;
    int j = 0;
    for (; j + 8 <= M; j += 8) {
      u64 a0 = s_cand[j + 0], a1 = s_cand[j + 1], a2 = s_cand[j + 2],
          a3 = s_cand[j + 3], a4 = s_cand[j + 4], a5 = s_cand[j + 5],
          a6 = s_cand[j + 6], a7 = s_cand[j + 7];
      r += (a0 > mine) + (a1 > mine) + (a2 > mine) + (a3 > mine) +
           (a4 > mine) + (a5 > mine) + (a6 > mine) + (a7 > mine);
    }
    for (; j < M; ++j) r += (s_cand[j] > mine) ? 1 : 0;
    if (r < TOPK) g_sel[(size_t)ft * TOPK + r] = mine;
  }
}

// ---------- Kernel B: suppression-mask generation (decode + IoU ballot) ----------
// grid = 640 (ft). Writes g_mask[ft*800 + i] (row-major, 4 u64 per row).
__global__ __launch_bounds__(256) void maskgen_kernel(
    const float* __restrict__ loc, const float* __restrict__ priors,
    const u64* __restrict__ g_sel, const int* __restrict__ g_nsel,
    u64* __restrict__ g_mask) {
  const int t = threadIdx.x;
  const int ft = blockIdx.x;
  const int b = ft / NFG;
  const int nsel = g_nsel[ft];

  __shared__ float4 s_box[256];
  __shared__ float s_area[256];
  __shared__ alignas(16) u64 s_sup[TOPK * 4];

  if (t < nsel) {
    u64 w = g_sel[(size_t)ft * TOPK + t];
    int p = P_BOX - (int)(uint32_t)(w & 0xFFFFFFFFull);
    float4 bx = decode_box(((const float4*)priors)[p],
                           ((const float4*)loc)[(size_t)b * P_BOX + p]);
    s_box[t] = bx;
    s_area[t] = (bx.z - bx.x) * (bx.w - bx.y);
  } else {
    s_box[t] = make_float4(0.f, 0.f, 0.f, 0.f);
    s_area[t] = 0.f;
  }
  for (int i = t; i < TOPK * 4; i += NTH) s_sup[i] = 0ull;
  __syncthreads();

  {
    int wv = t >> 6, l = t & 63;
    float4 bj[4];
    float aj[4];
#pragma unroll
    for (int cc = 0; cc < 4; ++cc) {
      bj[cc] = s_box[cc * 64 + l];
      aj[cc] = s_area[cc * 64 + l];
    }
    int cmax = (nsel + 63) >> 6;
    for (int i = wv; i < nsel; i += 4) {
      float4 bi = s_box[i];
      float ai = s_area[i];
      int c0 = i >> 6;
      for (int cc = c0; cc < cmax; ++cc) {
        int j = cc * 64 + l;
        float lx = fmaxf(bi.x, bj[cc].x), ly = fmaxf(bi.y, bj[cc].y);
        float rx = fminf(bi.z, bj[cc].z), ry = fminf(bi.w, bj[cc].w);
        float iw = fmaxf(rx - lx, 0.0f), ih = fmaxf(ry - ly, 0.0f);
        float inter = iw * ih;
        float uni = ai + aj[cc] - inter;
        float iou = inter / fmaxf(uni, 1e-12f);
        bool sup = (j > i) && (j < nsel) && (iou > 0.45f);
        u64 m = __ballot(sup);
        if (l == 0) s_sup[i * 4 + cc] = m;
      }
    }
  }
  __syncthreads();
  for (int i = t; i < TOPK * 4; i += NTH)
    g_mask[(size_t)ft * (TOPK * 4) + i] = s_sup[i];
}

// ---------- Kernel C: Jacobi alive-fixpoint + compact + output ----------
// grid = 672 (b*21 + c).
__global__ __launch_bounds__(256) void finalize_kernel(
    const float* __restrict__ loc, const float* __restrict__ priors,
    const u64* __restrict__ g_sel, const int* __restrict__ g_nsel,
    const u64* __restrict__ g_mask, float* __restrict__ out) {
  const int t = threadIdx.x;
  const int task = blockIdx.x;
  const int b = task / NCLS, c = task - b * NCLS;
  float* ob = out + (size_t)task * TOPK * 5;

  if (c == 0) {
    float4 z = make_float4(0.f, 0.f, 0.f, 0.f);
    for (int i = t; i < TOPK * 5 / 4; i += NTH) ((float4*)ob)[i] = z;
    return;
  }
  const int ft = b * NFG + (c - 1);
  const int nsel = g_nsel[ft];

  __shared__ float4 s_box[256];
  __shared__ float s_score[256];
  __shared__ u64 s_alive[4];
  __shared__ u64 s_wor[4][4];
  __shared__ int s_chg;
  __shared__ short s_kept[TOPK];
  __shared__ float s_out[TOPK * 5];

  // per-thread suppression row (registers), coalesced global load
  u64 r0 = 0, r1 = 0, r2 = 0, r3 = 0;
  if (t < TOPK) {
    const u64* mp = g_mask + (size_t)ft * (TOPK * 4) + t * 4;
    r0 = mp[0]; r1 = mp[1]; r2 = mp[2]; r3 = mp[3];
  }

  // decode selected for output rows
  if (t < nsel) {
    u64 w = g_sel[(size_t)ft * TOPK + t];
    uint32_t k = (uint32_t)(w >> 32);
    int p = P_BOX - (int)(uint32_t)(w & 0xFFFFFFFFull);
    float4 bx = decode_box(((const float4*)priors)[p],
                           ((const float4*)loc)[(size_t)b * P_BOX + p]);
    s_box[t] = bx;
    s_score[t] = key_score(k + NORM);
  } else {
    s_box[t] = make_float4(0.f, 0.f, 0.f, 0.f);
    s_score[t] = 0.f;
  }

  // valid bitmap
  int q0 = nsel, q1 = nsel - 64, q2 = nsel - 128, q3 = nsel - 192;
  u64 v0 = q0 >= 64 ? ~0ull : (q0 <= 0 ? 0ull : ((1ull << q0) - 1));
  u64 v1 = q1 >= 64 ? ~0ull : (q1 <= 0 ? 0ull : ((1ull << q1) - 1));
  u64 v2 = q2 >= 64 ? ~0ull : (q2 <= 0 ? 0ull : ((1ull << q2) - 1));
  u64 v3 = q3 >= 64 ? ~0ull : (q3 <= 0 ? 0ull : ((1ull << q3) - 1));
  if (t == 0) { s_alive[0] = v0; s_alive[1] = v1; s_alive[2] = v2; s_alive[3] = v3; }
  __syncthreads();

  // Jacobi fixpoint of alive[j] = valid[j] & !OR_{i alive} sup[i][j]
  // (well-founded recurrence: fixpoint unique == greedy NMS result; converges
  // in <= suppression-chain depth iterations, typically < 10)
  for (int it2 = 0; it2 <= TOPK; ++it2) {
    u64 a0 = s_alive[0], a1 = s_alive[1], a2 = s_alive[2], a3 = s_alive[3];
    bool mine = false;
    if (t < TOPK) {
      u64 aw = (t < 64) ? a0 : (t < 128) ? a1 : (t < 192) ? a2 : a3;
      mine = (aw >> (t & 63)) & 1ull;
    }
    u64 c0 = mine ? r0 : 0, c1 = mine ? r1 : 0, c2 = mine ? r2 : 0, c3 = mine ? r3 : 0;
#pragma unroll
    for (int off = 32; off > 0; off >>= 1) {
      c0 |= shfl_down_u64(c0, off);
      c1 |= shfl_down_u64(c1, off);
      c2 |= shfl_down_u64(c2, off);
      c3 |= shfl_down_u64(c3, off);
    }
    if ((t & 63) == 0) {
      int wv = t >> 6;
      s_wor[wv][0] = c0; s_wor[wv][1] = c1; s_wor[wv][2] = c2; s_wor[wv][3] = c3;
    }
    __syncthreads();
    if (t == 0) {
      u64 n0 = v0 & ~(s_wor[0][0] | s_wor[1][0] | s_wor[2][0] | s_wor[3][0]);
      u64 n1 = v1 & ~(s_wor[0][1] | s_wor[1][1] | s_wor[2][1] | s_wor[3][1]);
      u64 n2 = v2 & ~(s_wor[0][2] | s_wor[1][2] | s_wor[2][2] | s_wor[3][2]);
      u64 n3 = v3 & ~(s_wor[0][3] | s_wor[1][3] | s_wor[2][3] | s_wor[3][3]);
      s_chg = (n0 != a0) || (n1 != a1) || (n2 != a2) || (n3 != a3);
      s_alive[0] = n0; s_alive[1] = n1; s_alive[2] = n2; s_alive[3] = n3;
    }
    __syncthreads();
    if (!s_chg) break;
  }

  // compact kept to front via popcount ranks
  u64 w0 = s_alive[0], w1 = s_alive[1], w2 = s_alive[2], w3 = s_alive[3];
  int pc0 = __popcll(w0), pc01 = pc0 + __popcll(w1), pc012 = pc01 + __popcll(w2);
  int nk = pc012 + __popcll(w3);
  if (t < nsel) {
    int word = t >> 6, bit = t & 63;
    u64 wt = (word == 0) ? w0 : (word == 1) ? w1 : (word == 2) ? w2 : w3;
    if ((wt >> bit) & 1ull) {
      int base = (word == 0) ? 0 : (word == 1) ? pc0 : (word == 2) ? pc01 : pc012;
      int r = base + __popcll(wt & ((1ull << bit) - 1ull));
      s_kept[r] = (short)t;
    }
  }
  __syncthreads();

  if (t < TOPK) {
    float o0 = 0.f, o1 = 0.f, o2 = 0.f, o3 = 0.f, o4 = 0.f;
    if (t < nk) {
      int j = s_kept[t];
      o0 = s_score[j];
      float4 bx = s_box[j];
      o1 = bx.x; o2 = bx.y; o3 = bx.z; o4 = bx.w;
    }
    s_out[t * 5 + 0] = o0; s_out[t * 5 + 1] = o1; s_out[t * 5 + 2] = o2;
    s_out[t * 5 + 3] = o3; s_out[t * 5 + 4] = o4;
  }
  __syncthreads();
  for (int i = t; i < TOPK * 5 / 4; i += NTH)
    ((float4*)ob)[i] = ((float4*)s_out)[i];
}

// ---------- Fallback: fully fused (recompute) — only if ws is too small ----------
__global__ __launch_bounds__(256) void nms_fused_kernel(
    const float* __restrict__ loc, const float* __restrict__ conf,
    const float* __restrict__ priors, float* __restrict__ out) {
  const int t = threadIdx.x;
  const int task = blockIdx.x;
  const int b = task / NCLS, c = task - b * NCLS;
  float* ob = out + (size_t)task * TOPK * 5;
  if (c == 0) {
    float4 z = make_float4(0.f, 0.f, 0.f, 0.f);
    for (int i = t; i < TOPK * 5 / 4; i += NTH) ((float4*)ob)[i] = z;
    return;
  }
  __shared__ alignas(16) int s_hist[NBKT];
  __shared__ alignas(16) u64 s_cand[CAND_CAP];
  __shared__ u64 s_sel[TOPK];
  __shared__ float4 s_box[256];
  __shared__ float s_area[256];
  __shared__ float s_score[256];
  __shared__ u64 s_alive[4];
  __shared__ short s_kept[TOPK];
  __shared__ int s_wt[NTH / 64];
  __shared__ int s_res[3];
  __shared__ int s_cnt[3];
  __shared__ int s_m;
  u64* s_sup = (u64*)s_hist;
  int* s_S = (int*)s_cand;
  float* s_rows = (float*)s_cand;

  if (t == 0) { s_cnt[0] = 0; s_cnt[1] = 0; s_cnt[2] = 0; s_m = 0; }
  for (int i = t; i < NBKT; i += NTH) s_hist[i] = 0;

  uint32_t kv[NCH * 4];
  for (int ch = 0; ch < NCH; ++ch) {
    int p0 = ch * 1024 + 4 * t;
#pragma unroll
    for (int e = 0; e < 4; ++e) {
      int p = p0 + e;
      uint32_t k = LIM;
      if (p < P_BOX) {
        const float* cf = conf + (size_t)(b * P_BOX + p) * NCLS;
        float x[NCLS];
        float mx = -1e30f;
#pragma unroll
        for (int i = 0; i < NCLS; ++i) {
          float v = fminf(fmaxf(cf[i], -100.0f), 100.0f);
          x[i] = v;
          mx = fmaxf(mx, v);
        }
        float ssum = 0.0f, ec = 0.0f;
#pragma unroll
        for (int i = 0; i < NCLS; ++i) {
          float ex = expf(x[i] - mx);
          ssum += ex;
          if (i == c) ec = ex;
        }
        float sc = ec / ssum;
        float4 bx = decode_box(((const float4*)priors)[p],
                               ((const float4*)loc)[(size_t)b * P_BOX + p]);
        bool valid = (sc > 0.01f) && (bx.z > bx.x + 1e-6f) && (bx.w > bx.y + 1e-6f);
        k = score_key(valid ? sc : -1.0f) - NORM;
      }
      kv[ch * 4 + e] = k;
    }
  }
  __syncthreads();
#pragma unroll
  for (int j = 0; j < NCH * 4; ++j)
    if (kv[j] < LIM) atomicAdd(&s_hist[kv[j] >> 15], 1);
  __syncthreads();
  int3 r1 = select_bucket(s_hist, s_S, s_wt, s_res, TOPK, t);
  uint32_t Tp = (uint32_t)r1.x << 15;
  int M = r1.y;
  bool ex = false;
  uint32_t Tex = 0, I = 0;
  if (M > CAND_CAP) {
    uint32_t B1 = (uint32_t)r1.x;
    int above1 = r1.z;
    __syncthreads();
    for (int i = t; i < NBKT; i += NTH) s_hist[i] = 0;
    __syncthreads();
#pragma unroll
    for (int j = 0; j < NCH * 4; ++j)
      if (kv[j] < LIM && (kv[j] >> 15) == B1)
        atomicAdd(&s_hist[(kv[j] >> 4) & (NBKT - 1)], 1);
    __syncthreads();
    int3 r2 = select_bucket(s_hist, s_S, s_wt, s_res, TOPK - above1, t);
    Tp = (B1 << 15) + ((uint32_t)r2.x << 4);
    M = above1 + r2.y;
    if (M > CAND_CAP) {
      int it = 0;
      uint32_t lo = Tp, hi = LIM;
      while (hi - lo > 1) {
        uint32_t mid = lo + ((hi - lo) >> 1);
        int cnt = block_count(cnt_ge(kv, mid), t, s_cnt, it);
        if (cnt >= TOPK) lo = mid; else hi = mid;
      }
      Tex = lo;
      int G = block_count(cnt_ge(kv, Tex + 1), t, s_cnt, it);
      int R = TOPK - G;
      uint32_t lo2 = 1, hi2 = P_BOX + 1;
      while (hi2 - lo2 > 1) {
        uint32_t mid = lo2 + ((hi2 - lo2) >> 1);
        int cnt = block_count(cnt_eq_idx(kv, t, Tex, mid), t, s_cnt, it);
        if (cnt >= R) lo2 = mid; else hi2 = mid;
      }
      I = lo2;
      ex = true;
    }
  }
  __syncthreads();
#pragma unroll
  for (int ch = 0; ch < NCH; ++ch) {
#pragma unroll
    for (int e = 0; e < 4; ++e) {
      uint32_t k = kv[ch * 4 + e];
      if (k < LIM) {
        int p = ch * 1024 + 4 * t + e;
        bool take = ex ? (k > Tex || (k == Tex && (uint32_t)(P_BOX - p) >= I))
                       : (k >= Tp);
        if (take) {
          int ix = atomicAdd(&s_m, 1);
          if (ix < CAND_CAP) s_cand[ix] = ((u64)k << 32) | (uint32_t)(P_BOX - p);
        }
      }
    }
  }
  __syncthreads();
  M = min(s_m, CAND_CAP);
  int nsel = min(M, TOPK);
  for (int ci = t; ci < M; ci += NTH) {
    u64 mine = s_cand[ci];
    int r = 0;
    for (int j = 0; j < M; ++j) r += (s_cand[j] > mine) ? 1 : 0;
    if (r < TOPK) s_sel[r] = mine;
  }
  __syncthreads();
  if (t < nsel) {
    u64 w = s_sel[t];
    uint32_t k = (uint32_t)(w >> 32);
    int p = P_BOX - (int)(uint32_t)(w & 0xFFFFFFFFull);
    float4 bx = decode_box(((const float4*)priors)[p],
                           ((const float4*)loc)[(size_t)b * P_BOX + p]);
    s_box[t] = bx;
    s_area[t] = (bx.z - bx.x) * (bx.w - bx.y);
    s_score[t] = key_score(k + NORM);
  } else {
    s_box[t] = make_float4(0.f, 0.f, 0.f, 0.f);
    s_area[t] = 0.f;
    s_score[t] = 0.f;
  }
  for (int i = t; i < TOPK * 4; i += NTH) s_sup[i] = 0ull;
  __syncthreads();
  {
    int wv = t >> 6, l = t & 63;
    float4 bj[4];
    float aj[4];
#pragma unroll
    for (int cc = 0; cc < 4; ++cc) {
      bj[cc] = s_box[cc * 64 + l];
      aj[cc] = s_area[cc * 64 + l];
    }
    int cmax = (nsel + 63) >> 6;
    for (int i = wv; i < nsel; i += 4) {
      float4 bi = s_box[i];
      float ai = s_area[i];
      int c0 = i >> 6;
      for (int cc = c0; cc < cmax; ++cc) {
        int j = cc * 64 + l;
        float lx = fmaxf(bi.x, bj[cc].x), ly = fmaxf(bi.y, bj[cc].y);
        float rx = fminf(bi.z, bj[cc].z), ry = fminf(bi.w, bj[cc].w);
        float iw = fmaxf(rx - lx, 0.0f), ih = fmaxf(ry - ly, 0.0f);
        float inter = iw * ih;
        float uni = ai + aj[cc] - inter;
        float iou = inter / fmaxf(uni, 1e-12f);
        bool sup = (j > i) && (j < nsel) && (iou > 0.45f);
        u64 m = __ballot(sup);
        if (l == 0) s_sup[i * 4 + cc] = m;
      }
    }
  }
  __syncthreads();
  if (t == 0) {
    u64 aw0, aw1, aw2, aw3;
    int r0 = nsel, r1b = nsel - 64, r2b = nsel - 128, r3b = nsel - 192;
    aw0 = r0 >= 64 ? ~0ull : (r0 <= 0 ? 0ull : ((1ull << r0) - 1));
    aw1 = r1b >= 64 ? ~0ull : (r1b <= 0 ? 0ull : ((1ull << r1b) - 1));
    aw2 = r2b >= 64 ? ~0ull : (r2b <= 0 ? 0ull : ((1ull << r2b) - 1));
    aw3 = r3b >= 64 ? ~0ull : (r3b <= 0 ? 0ull : ((1ull << r3b) - 1));
    for (int i = 0; i < nsel; ++i) {
      int w = i >> 6;
      u64 cur = (w == 0) ? aw0 : (w == 1) ? aw1 : (w == 2) ? aw2 : aw3;
      if ((cur >> (i & 63)) & 1ull) {
        aw0 &= ~s_sup[i * 4 + 0]; aw1 &= ~s_sup[i * 4 + 1];
        aw2 &= ~s_sup[i * 4 + 2]; aw3 &= ~s_sup[i * 4 + 3];
      }
    }
    s_alive[0] = aw0; s_alive[1] = aw1; s_alive[2] = aw2; s_alive[3] = aw3;
  }
  __syncthreads();
  u64 w0 = s_alive[0], w1 = s_alive[1], w2 = s_alive[2], w3 = s_alive[3];
  int pc0 = __popcll(w0), pc01 = pc0 + __popcll(w1), pc012 = pc01 + __popcll(w2);
  int nk = pc012 + __popcll(w3);
  if (t < nsel) {
    int word = t >> 6, bit = t & 63;
    u64 wt = (word == 0) ? w0 : (word == 1) ? w1 : (word == 2) ? w2 : w3;
    if ((wt >> bit) & 1ull) {
      int base = (word == 0) ? 0 : (word == 1) ? pc0 : (word == 2) ? pc01 : pc012;
      int r = base + __popcll(wt & ((1ull << bit) - 1ull));
      s_kept[r] = (short)t;
    }
  }
  __syncthreads();
  if (t < TOPK) {
    float r0 = 0.f, r1b = 0.f, r2b = 0.f, r3b = 0.f, r4 = 0.f;
    if (t < nk) {
      int j = s_kept[t];
      r0 = s_score[j];
      float4 bx = s_box[j];
      r1b = bx.x; r2b = bx.y; r3b = bx.z; r4 = bx.w;
    }
    s_rows[t * 5 + 0] = r0; s_rows[t * 5 + 1] = r1b; s_rows[t * 5 + 2] = r2b;
    s_rows[t * 5 + 3] = r3b; s_rows[t * 5 + 4] = r4;
  }
  __syncthreads();
  for (int i = t; i < TOPK * 5 / 4; i += NTH)
    ((float4*)ob)[i] = ((float4*)s_rows)[i];
}

extern "C" void kernel_launch(void* const* d_in, const int* in_sizes, int n_in,
                              void* d_out, int out_size, void* d_ws, size_t ws_size,
                              hipStream_t stream) {
  (void)in_sizes;
  (void)n_in;
  (void)out_size;
  const float* loc = (const float*)d_in[0];     // [B,P,4]
  const float* conf = (const float*)d_in[1];    // [B,P,21]
  const float* priors = (const float*)d_in[2];  // [P,4]
  float* out = (float*)d_out;                   // [B,21,200,5]

  size_t keys_bytes = (size_t)BATCH * NFG * P_BOX * sizeof(uint32_t);  // 22.35 MB
  size_t sel_bytes = (size_t)BATCH * NFG * TOPK * sizeof(u64);         // 1.02 MB
  size_t nsel_bytes = (size_t)BATCH * NFG * sizeof(int);               // 2.5 KB
  size_t mask_bytes = (size_t)BATCH * NFG * TOPK * 4 * sizeof(u64);    // 4.10 MB
  if (ws_size >= keys_bytes + sel_bytes + nsel_bytes + mask_bytes) {
    char* wp = (char*)d_ws;
    uint32_t* keys = (uint32_t*)wp;
    u64* g_sel = (u64*)(wp + keys_bytes);
    int* g_nsel = (int*)(wp + keys_bytes + sel_bytes);
    u64* g_mask = (u64*)(wp + keys_bytes + sel_bytes + nsel_bytes);
    int nprep = (NBOX_TOTAL + 255) / 256;
    prep_kernel<<<nprep, 256, 0, stream>>>(loc, conf, priors, keys);
    select_kernel<<<BATCH * NFG, NTH, 0, stream>>>(keys, g_sel, g_nsel);
    maskgen_kernel<<<BATCH * NFG, NTH, 0, stream>>>(loc, priors, g_sel, g_nsel, g_mask);
    finalize_kernel<<<BATCH * NCLS, NTH, 0, stream>>>(loc, priors, g_sel, g_nsel, g_mask, out);
  } else {
    nms_fused_kernel<<<BATCH * NCLS, NTH, 0, stream>>>(loc, conf, priors, out);
  }
}

// Round 7
// 139.940 us; speedup vs baseline: 1.3567x; 1.2323x over previous
//
#include <hip/hip_runtime.h>
#include <cstdint>

#define P_BOX 8732
#define NBOX_TOTAL 279424  // 32*8732
#define BATCH 32
#define NCLS 21
#define NFG 20
#define TOPK 200
#define NTH 256
#define NCH 9  // chunks of 1024 keys; chunk 8 partial (t < 135)
#define CAND_CAP 512
#define NBKT 2048
#define NORM 0xBC23D70Bu  // score_key(0.01f)+1 ; stored keys are pre-normalized
#define LIM (1u << 26)    // normalized key < LIM  <=>  eligible (score > 0.01)
#define CONF_F4 1466976   // 32*8732*21/4

typedef unsigned long long u64;

__device__ __forceinline__ uint32_t score_key(float m) {
  uint32_t b = __float_as_uint(m);
  return (b & 0x80000000u) ? ~b : (b | 0x80000000u);
}
__device__ __forceinline__ float key_score(uint32_t k) {
  uint32_t b = (k & 0x80000000u) ? (k ^ 0x80000000u) : ~k;
  return __uint_as_float(b);
}

// Exactly mirrors reference _decode (fp32).
__device__ __forceinline__ float4 decode_box(const float4 pr, const float4 lc) {
  float px = fmaxf(pr.x, 1e-6f), py = fmaxf(pr.y, 1e-6f);
  float pw = fmaxf(pr.z, 1e-6f), ph = fmaxf(pr.w, 1e-6f);
  float cx = px + lc.x * 0.1f * pw;
  float cy = py + lc.y * 0.1f * ph;
  float lw = fminf(fmaxf(lc.z * 0.2f, -4.0f), 4.0f);
  float lh = fminf(fmaxf(lc.w * 0.2f, -4.0f), 4.0f);
  float w = pw * expf(lw);
  float h = ph * expf(lh);
  float4 r;
  r.x = fminf(fmaxf(cx - 0.5f * w, 0.0f), 1.0f);
  r.y = fminf(fmaxf(cy - 0.5f * h, 0.0f), 1.0f);
  r.z = fminf(fmaxf(cx + 0.5f * w, 0.0f), 1.0f);
  r.w = fminf(fmaxf(cy + 0.5f * h, 0.0f), 1.0f);
  return r;
}

// Prep: 256 boxes/block. Stage conf in LDS; emit normalized masked score-keys,
// class-major: keys[(b*20 + c-1)*P_BOX + p].
__global__ __launch_bounds__(256) void prep_kernel(
    const float* __restrict__ loc, const float* __restrict__ conf,
    const float* __restrict__ priors, uint32_t* __restrict__ keys) {
  __shared__ float s_conf[256 * 21];
  const int t = threadIdx.x;
  const int blk = blockIdx.x;
  const float4* cf4 = (const float4*)conf;
  size_t base4 = (size_t)blk * 1344;
#pragma unroll
  for (int i = t; i < 1344; i += 256) {
    size_t g4 = base4 + i;
    if (g4 < CONF_F4) ((float4*)s_conf)[i] = cf4[g4];
  }
  __syncthreads();
  int g = blk * 256 + t;
  if (g >= NBOX_TOTAL) return;
  int b = g / P_BOX, p = g - b * P_BOX;
  float x[NCLS];
  float mx = -1e30f;
#pragma unroll
  for (int i = 0; i < NCLS; ++i) {
    float v = fminf(fmaxf(s_conf[t * 21 + i], -100.0f), 100.0f);
    x[i] = v;
    mx = fmaxf(mx, v);
  }
  float s = 0.0f;
#pragma unroll
  for (int i = 0; i < NCLS; ++i) {
    x[i] = expf(x[i] - mx);
    s += x[i];
  }
  float4 bx = decode_box(((const float4*)priors)[p], ((const float4*)loc)[g]);
  bool bok = (bx.z > bx.x + 1e-6f) && (bx.w > bx.y + 1e-6f);
#pragma unroll
  for (int ci = 1; ci < NCLS; ++ci) {
    float sc = x[ci] / s;
    float m = (bok && sc > 0.01f) ? sc : -1.0f;
    keys[((size_t)(b * NFG) + (ci - 1)) * P_BOX + p] = score_key(m) - NORM;
  }
}

__device__ __forceinline__ int cnt_ge(const uint32_t* kv, uint32_t X) {
  int n = 0;
#pragma unroll
  for (int j = 0; j < NCH * 4; ++j) n += (kv[j] >= X && kv[j] < LIM) ? 1 : 0;
  return n;
}
__device__ __forceinline__ int cnt_eq_idx(const uint32_t* kv, int t, uint32_t T, uint32_t I) {
  int n = 0;
#pragma unroll
  for (int ch = 0; ch < NCH; ++ch) {
#pragma unroll
    for (int e = 0; e < 4; ++e) {
      int p = ch * 1024 + t * 4 + e;
      n += (kv[ch * 4 + e] == T && (uint32_t)(P_BOX - p) >= I) ? 1 : 0;
    }
  }
  return n;
}

__device__ __forceinline__ int block_count(int v, int t, int* s_cnt, int& it) {
#pragma unroll
  for (int o = 32; o > 0; o >>= 1) v += __shfl_down(v, o, 64);
  int slot = it % 3;
  if (t == 0) s_cnt[(it + 1) % 3] = 0;
  if ((t & 63) == 0) atomicAdd(&s_cnt[slot], v);
  __syncthreads();
  int r = s_cnt[slot];
  ++it;
  return r;
}

__device__ __forceinline__ int3 select_bucket(const int* s_hist, int* s_S,
                                              int* s_wt, int* s_res, int need,
                                              int t) {
  const int BPT = NBKT / NTH;  // 8
  int base = t * BPT;
  int ps = 0;
#pragma unroll
  for (int i = 0; i < BPT; ++i) ps += s_hist[base + i];
  int l = t & 63, w = t >> 6;
  int v = ps;
#pragma unroll
  for (int off = 1; off < 64; off <<= 1) {
    int o = __shfl_down(v, off, 64);
    v += (l + off < 64) ? o : 0;
  }
  if (l == 0) s_wt[w] = v;
  __syncthreads();
  int hi = 0;
#pragma unroll
  for (int w2 = 0; w2 < NTH / 64; ++w2) hi += (w2 > w) ? s_wt[w2] : 0;
  int S = v + hi;
  s_S[t] = S;
  __syncthreads();
  if (t == 0 && s_S[0] < need) {
    s_res[0] = 0; s_res[1] = s_S[0]; s_res[2] = 0;
  } else if (s_S[t] >= need && (t == NTH - 1 || s_S[t + 1] < need)) {
    int suf = (t == NTH - 1) ? 0 : s_S[t + 1];
    int B = base, M = 0;
    for (int j = base + BPT - 1; j >= base; --j) {
      suf += s_hist[j];
      if (suf >= need) { B = j; M = suf; break; }
    }
    s_res[0] = B; s_res[1] = M; s_res[2] = M - s_hist[B];
  }
  __syncthreads();
  return make_int3(s_res[0], s_res[1], s_res[2]);
}

// ---------- Kernel A: per-fg-task top-200 selection -> ws ----------
__global__ __launch_bounds__(256) void select_kernel(
    const uint32_t* __restrict__ keys, u64* __restrict__ g_sel,
    int* __restrict__ g_nsel) {
  const int t = threadIdx.x;
  const int ft = blockIdx.x;

  __shared__ alignas(16) int s_hist[NBKT];
  __shared__ alignas(16) u64 s_cand[CAND_CAP];
  __shared__ int s_wt[NTH / 64];
  __shared__ int s_res[3];
  __shared__ int s_cnt[3];
  __shared__ int s_m;
  int* s_S = (int*)s_cand;

  if (t == 0) { s_cnt[0] = 0; s_cnt[1] = 0; s_cnt[2] = 0; s_m = 0; }
  for (int i = t; i < NBKT; i += NTH) s_hist[i] = 0;

  uint32_t kv[NCH * 4];
  {
    const uint4* kp = (const uint4*)(keys + (size_t)ft * P_BOX);
#pragma unroll
    for (int ch = 0; ch < 8; ++ch) {
      uint4 v = kp[ch * 256 + t];
      kv[ch * 4 + 0] = v.x; kv[ch * 4 + 1] = v.y;
      kv[ch * 4 + 2] = v.z; kv[ch * 4 + 3] = v.w;
    }
    if (t < 135) {
      uint4 v = kp[2048 + t];
      kv[32] = v.x; kv[33] = v.y; kv[34] = v.z; kv[35] = v.w;
    } else {
      kv[32] = LIM; kv[33] = LIM; kv[34] = LIM; kv[35] = LIM;
    }
  }
  __syncthreads();

#pragma unroll
  for (int j = 0; j < NCH * 4; ++j)
    if (kv[j] < LIM) atomicAdd(&s_hist[kv[j] >> 15], 1);
  __syncthreads();
  int3 r1 = select_bucket(s_hist, s_S, s_wt, s_res, TOPK, t);
  uint32_t Tp = (uint32_t)r1.x << 15;
  int M = r1.y;
  bool ex = false;
  uint32_t Tex = 0, I = 0;

  if (M > CAND_CAP) {
    uint32_t B1 = (uint32_t)r1.x;
    int above1 = r1.z;
    __syncthreads();
    for (int i = t; i < NBKT; i += NTH) s_hist[i] = 0;
    __syncthreads();
#pragma unroll
    for (int j = 0; j < NCH * 4; ++j)
      if (kv[j] < LIM && (kv[j] >> 15) == B1)
        atomicAdd(&s_hist[(kv[j] >> 4) & (NBKT - 1)], 1);
    __syncthreads();
    int3 r2 = select_bucket(s_hist, s_S, s_wt, s_res, TOPK - above1, t);
    Tp = (B1 << 15) + ((uint32_t)r2.x << 4);
    M = above1 + r2.y;
    if (M > CAND_CAP) {
      int it = 0;
      uint32_t lo = Tp, hi = LIM;
      while (hi - lo > 1) {
        uint32_t mid = lo + ((hi - lo) >> 1);
        int cnt = block_count(cnt_ge(kv, mid), t, s_cnt, it);
        if (cnt >= TOPK) lo = mid; else hi = mid;
      }
      Tex = lo;
      int G = block_count(cnt_ge(kv, Tex + 1), t, s_cnt, it);
      int R = TOPK - G;
      uint32_t lo2 = 1, hi2 = P_BOX + 1;
      while (hi2 - lo2 > 1) {
        uint32_t mid = lo2 + ((hi2 - lo2) >> 1);
        int cnt = block_count(cnt_eq_idx(kv, t, Tex, mid), t, s_cnt, it);
        if (cnt >= R) lo2 = mid; else hi2 = mid;
      }
      I = lo2;
      ex = true;
    }
  }
  __syncthreads();

#pragma unroll
  for (int ch = 0; ch < NCH; ++ch) {
#pragma unroll
    for (int e = 0; e < 4; ++e) {
      uint32_t k = kv[ch * 4 + e];
      if (k < LIM) {
        int p = ch * 1024 + 4 * t + e;
        bool take = ex ? (k > Tex || (k == Tex && (uint32_t)(P_BOX - p) >= I))
                       : (k >= Tp);
        if (take) {
          int ix = atomicAdd(&s_m, 1);
          if (ix < CAND_CAP) s_cand[ix] = ((u64)k << 32) | (uint32_t)(P_BOX - p);
        }
      }
    }
  }
  __syncthreads();
  M = min(s_m, CAND_CAP);
  int nsel = min(M, TOPK);
  if (t == 0) g_nsel[ft] = nsel;

  for (int ci = t; ci < M; ci += NTH) {
    u64 mine = s_cand[ci];
    int r = 0;
    int j = 0;
    for (; j + 8 <= M; j += 8) {
      u64 a0 = s_cand[j + 0], a1 = s_cand[j + 1], a2 = s_cand[j + 2],
          a3 = s_cand[j + 3], a4 = s_cand[j + 4], a5 = s_cand[j + 5],
          a6 = s_cand[j + 6], a7 = s_cand[j + 7];
      r += (a0 > mine) + (a1 > mine) + (a2 > mine) + (a3 > mine) +
           (a4 > mine) + (a5 > mine) + (a6 > mine) + (a7 > mine);
    }
    for (; j < M; ++j) r += (s_cand[j] > mine) ? 1 : 0;
    if (r < TOPK) g_sel[(size_t)ft * TOPK + r] = mine;
  }
}

// ---------- Kernel B: banded COLUMN suppression masks ----------
// grid = 640*4. Block (ft, band) computes, for every column j, one u64 word:
// bit (i-band*64) set iff box i suppresses box j (i<j, iou>0.45).
// Layout: g_mask[ft*800 + band*200 + j]  (coalesced write AND read).
// No ballots, no divergent LDS writes: pure per-thread register bit-set.
__global__ __launch_bounds__(256) void maskgen_kernel(
    const float* __restrict__ loc, const float* __restrict__ priors,
    const u64* __restrict__ g_sel, const int* __restrict__ g_nsel,
    u64* __restrict__ g_mask) {
  const int t = threadIdx.x;
  const int ft = blockIdx.x >> 2;
  const int band = blockIdx.x & 3;
  const int b = ft / NFG;
  const int nsel = g_nsel[ft];

  __shared__ float4 s_box[TOPK];
  __shared__ float s_area[TOPK];

  if (t < TOPK) {
    if (t < nsel) {
      u64 w = g_sel[(size_t)ft * TOPK + t];
      int p = P_BOX - (int)(uint32_t)(w & 0xFFFFFFFFull);
      float4 bx = decode_box(((const float4*)priors)[p],
                             ((const float4*)loc)[(size_t)b * P_BOX + p]);
      s_box[t] = bx;
      s_area[t] = (bx.z - bx.x) * (bx.w - bx.y);
    } else {
      s_box[t] = make_float4(0.f, 0.f, 0.f, 0.f);
      s_area[t] = 0.f;
    }
  }
  __syncthreads();

  float4 bj = make_float4(0.f, 0.f, 0.f, 0.f);
  float aj = 0.f;
  if (t < nsel) { bj = s_box[t]; aj = s_area[t]; }
  const int base = band * 64;
  const int iend = min(base + 64, nsel);
  u64 w = 0;
#pragma unroll 4
  for (int i = base; i < iend; ++i) {
    float4 bi = s_box[i];   // broadcast (same addr across lanes) — conflict-free
    float ai = s_area[i];
    float lx = fmaxf(bi.x, bj.x), ly = fmaxf(bi.y, bj.y);
    float rx = fminf(bi.z, bj.z), ry = fminf(bi.w, bj.w);
    float iw = fmaxf(rx - lx, 0.0f), ih = fmaxf(ry - ly, 0.0f);
    float inter = iw * ih;
    float uni = ai + aj - inter;
    float iou = inter / fmaxf(uni, 1e-12f);
    bool sup = (i < t) && (t < nsel) && (iou > 0.45f);
    w |= ((u64)sup) << (i - base);
  }
  if (t < TOPK)
    g_mask[(size_t)ft * (TOPK * 4) + band * TOPK + t] = w;
}

// ---------- Kernel C: column-Jacobi alive-fixpoint + compact + output ----------
// grid = 672 (b*21 + c). Thread j holds colmask[j] (who suppresses j).
__global__ __launch_bounds__(256) void finalize_kernel(
    const float* __restrict__ loc, const float* __restrict__ priors,
    const u64* __restrict__ g_sel, const int* __restrict__ g_nsel,
    const u64* __restrict__ g_mask, float* __restrict__ out) {
  const int t = threadIdx.x;
  const int task = blockIdx.x;
  const int b = task / NCLS, c = task - b * NCLS;
  float* ob = out + (size_t)task * TOPK * 5;

  if (c == 0) {
    float4 z = make_float4(0.f, 0.f, 0.f, 0.f);
    for (int i = t; i < TOPK * 5 / 4; i += NTH) ((float4*)ob)[i] = z;
    return;
  }
  const int ft = b * NFG + (c - 1);
  const int nsel = g_nsel[ft];

  __shared__ float4 s_box[256];
  __shared__ float s_score[256];
  __shared__ u64 s_alive[4];
  __shared__ u64 s_nxt[4];
  __shared__ int s_chg;
  __shared__ short s_kept[TOPK];
  __shared__ float s_out[TOPK * 5];

  // column mask (registers), coalesced loads
  u64 cm0 = 0, cm1 = 0, cm2 = 0, cm3 = 0;
  if (t < TOPK) {
    const u64* mp = g_mask + (size_t)ft * (TOPK * 4);
    cm0 = mp[t]; cm1 = mp[TOPK + t]; cm2 = mp[2 * TOPK + t]; cm3 = mp[3 * TOPK + t];
  }

  // decode selected for output rows
  if (t < nsel) {
    u64 w = g_sel[(size_t)ft * TOPK + t];
    uint32_t k = (uint32_t)(w >> 32);
    int p = P_BOX - (int)(uint32_t)(w & 0xFFFFFFFFull);
    float4 bx = decode_box(((const float4*)priors)[p],
                           ((const float4*)loc)[(size_t)b * P_BOX + p]);
    s_box[t] = bx;
    s_score[t] = key_score(k + NORM);
  } else {
    s_box[t] = make_float4(0.f, 0.f, 0.f, 0.f);
    s_score[t] = 0.f;
  }

  // valid bitmap
  int q0 = nsel, q1 = nsel - 64, q2 = nsel - 128, q3 = nsel - 192;
  u64 v0 = q0 >= 64 ? ~0ull : (q0 <= 0 ? 0ull : ((1ull << q0) - 1));
  u64 v1 = q1 >= 64 ? ~0ull : (q1 <= 0 ? 0ull : ((1ull << q1) - 1));
  u64 v2 = q2 >= 64 ? ~0ull : (q2 <= 0 ? 0ull : ((1ull << q2) - 1));
  u64 v3 = q3 >= 64 ? ~0ull : (q3 <= 0 ? 0ull : ((1ull << q3) - 1));
  if (t == 0) { s_alive[0] = v0; s_alive[1] = v1; s_alive[2] = v2; s_alive[3] = v3; }
  __syncthreads();

  // Jacobi fixpoint of alive[j] = valid[j] & !OR_i(alive[i] & sup[i][j])
  // (same recurrence F as the R6-verified row form; converges in
  //  <= suppression-chain depth iterations, typically < 10)
  const bool validj = (t < nsel);
  for (int it2 = 0; it2 <= TOPK; ++it2) {
    u64 a0 = s_alive[0], a1 = s_alive[1], a2 = s_alive[2], a3 = s_alive[3];
    bool sup = ((cm0 & a0) | (cm1 & a1) | (cm2 & a2) | (cm3 & a3)) != 0ull;
    bool na = validj && !sup;
    u64 m = __ballot(na);
    if ((t & 63) == 0) s_nxt[t >> 6] = m;
    __syncthreads();
    if (t == 0) {
      s_chg = (s_nxt[0] != a0) || (s_nxt[1] != a1) ||
              (s_nxt[2] != a2) || (s_nxt[3] != a3);
      s_alive[0] = s_nxt[0]; s_alive[1] = s_nxt[1];
      s_alive[2] = s_nxt[2]; s_alive[3] = s_nxt[3];
    }
    __syncthreads();
    if (!s_chg) break;
  }

  // compact kept to front via popcount ranks
  u64 w0 = s_alive[0], w1 = s_alive[1], w2 = s_alive[2], w3 = s_alive[3];
  int pc0 = __popcll(w0), pc01 = pc0 + __popcll(w1), pc012 = pc01 + __popcll(w2);
  int nk = pc012 + __popcll(w3);
  if (t < nsel) {
    int word = t >> 6, bit = t & 63;
    u64 wt = (word == 0) ? w0 : (word == 1) ? w1 : (word == 2) ? w2 : w3;
    if ((wt >> bit) & 1ull) {
      int base = (word == 0) ? 0 : (word == 1) ? pc0 : (word == 2) ? pc01 : pc012;
      int r = base + __popcll(wt & ((1ull << bit) - 1ull));
      s_kept[r] = (short)t;
    }
  }
  __syncthreads();

  if (t < TOPK) {
    float o0 = 0.f, o1 = 0.f, o2 = 0.f, o3 = 0.f, o4 = 0.f;
    if (t < nk) {
      int j = s_kept[t];
      o0 = s_score[j];
      float4 bx = s_box[j];
      o1 = bx.x; o2 = bx.y; o3 = bx.z; o4 = bx.w;
    }
    s_out[t * 5 + 0] = o0; s_out[t * 5 + 1] = o1; s_out[t * 5 + 2] = o2;
    s_out[t * 5 + 3] = o3; s_out[t * 5 + 4] = o4;
  }
  __syncthreads();
  for (int i = t; i < TOPK * 5 / 4; i += NTH)
    ((float4*)ob)[i] = ((float4*)s_out)[i];
}

// ---------- Fallback: fully fused (recompute) — only if ws is too small ----------
__global__ __launch_bounds__(256) void nms_fused_kernel(
    const float* __restrict__ loc, const float* __restrict__ conf,
    const float* __restrict__ priors, float* __restrict__ out) {
  const int t = threadIdx.x;
  const int task = blockIdx.x;
  const int b = task / NCLS, c = task - b * NCLS;
  float* ob = out + (size_t)task * TOPK * 5;
  if (c == 0) {
    float4 z = make_float4(0.f, 0.f, 0.f, 0.f);
    for (int i = t; i < TOPK * 5 / 4; i += NTH) ((float4*)ob)[i] = z;
    return;
  }
  __shared__ alignas(16) int s_hist[NBKT];
  __shared__ alignas(16) u64 s_cand[CAND_CAP];
  __shared__ u64 s_sel[TOPK];
  __shared__ float4 s_box[256];
  __shared__ float s_area[256];
  __shared__ float s_score[256];
  __shared__ u64 s_alive[4];
  __shared__ short s_kept[TOPK];
  __shared__ int s_wt[NTH / 64];
  __shared__ int s_res[3];
  __shared__ int s_cnt[3];
  __shared__ int s_m;
  u64* s_sup = (u64*)s_hist;
  int* s_S = (int*)s_cand;
  float* s_rows = (float*)s_cand;

  if (t == 0) { s_cnt[0] = 0; s_cnt[1] = 0; s_cnt[2] = 0; s_m = 0; }
  for (int i = t; i < NBKT; i += NTH) s_hist[i] = 0;

  uint32_t kv[NCH * 4];
  for (int ch = 0; ch < NCH; ++ch) {
    int p0 = ch * 1024 + 4 * t;
#pragma unroll
    for (int e = 0; e < 4; ++e) {
      int p = p0 + e;
      uint32_t k = LIM;
      if (p < P_BOX) {
        const float* cf = conf + (size_t)(b * P_BOX + p) * NCLS;
        float x[NCLS];
        float mx = -1e30f;
#pragma unroll
        for (int i = 0; i < NCLS; ++i) {
          float v = fminf(fmaxf(cf[i], -100.0f), 100.0f);
          x[i] = v;
          mx = fmaxf(mx, v);
        }
        float ssum = 0.0f, ec = 0.0f;
#pragma unroll
        for (int i = 0; i < NCLS; ++i) {
          float ex = expf(x[i] - mx);
          ssum += ex;
          if (i == c) ec = ex;
        }
        float sc = ec / ssum;
        float4 bx = decode_box(((const float4*)priors)[p],
                               ((const float4*)loc)[(size_t)b * P_BOX + p]);
        bool valid = (sc > 0.01f) && (bx.z > bx.x + 1e-6f) && (bx.w > bx.y + 1e-6f);
        k = score_key(valid ? sc : -1.0f) - NORM;
      }
      kv[ch * 4 + e] = k;
    }
  }
  __syncthreads();
#pragma unroll
  for (int j = 0; j < NCH * 4; ++j)
    if (kv[j] < LIM) atomicAdd(&s_hist[kv[j] >> 15], 1);
  __syncthreads();
  int3 r1 = select_bucket(s_hist, s_S, s_wt, s_res, TOPK, t);
  uint32_t Tp = (uint32_t)r1.x << 15;
  int M = r1.y;
  bool ex = false;
  uint32_t Tex = 0, I = 0;
  if (M > CAND_CAP) {
    uint32_t B1 = (uint32_t)r1.x;
    int above1 = r1.z;
    __syncthreads();
    for (int i = t; i < NBKT; i += NTH) s_hist[i] = 0;
    __syncthreads();
#pragma unroll
    for (int j = 0; j < NCH * 4; ++j)
      if (kv[j] < LIM && (kv[j] >> 15) == B1)
        atomicAdd(&s_hist[(kv[j] >> 4) & (NBKT - 1)], 1);
    __syncthreads();
    int3 r2 = select_bucket(s_hist, s_S, s_wt, s_res, TOPK - above1, t);
    Tp = (B1 << 15) + ((uint32_t)r2.x << 4);
    M = above1 + r2.y;
    if (M > CAND_CAP) {
      int it = 0;
      uint32_t lo = Tp, hi = LIM;
      while (hi - lo > 1) {
        uint32_t mid = lo + ((hi - lo) >> 1);
        int cnt = block_count(cnt_ge(kv, mid), t, s_cnt, it);
        if (cnt >= TOPK) lo = mid; else hi = mid;
      }
      Tex = lo;
      int G = block_count(cnt_ge(kv, Tex + 1), t, s_cnt, it);
      int R = TOPK - G;
      uint32_t lo2 = 1, hi2 = P_BOX + 1;
      while (hi2 - lo2 > 1) {
        uint32_t mid = lo2 + ((hi2 - lo2) >> 1);
        int cnt = block_count(cnt_eq_idx(kv, t, Tex, mid), t, s_cnt, it);
        if (cnt >= R) lo2 = mid; else hi2 = mid;
      }
      I = lo2;
      ex = true;
    }
  }
  __syncthreads();
#pragma unroll
  for (int ch = 0; ch < NCH; ++ch) {
#pragma unroll
    for (int e = 0; e < 4; ++e) {
      uint32_t k = kv[ch * 4 + e];
      if (k < LIM) {
        int p = ch * 1024 + 4 * t + e;
        bool take = ex ? (k > Tex || (k == Tex && (uint32_t)(P_BOX - p) >= I))
                       : (k >= Tp);
        if (take) {
          int ix = atomicAdd(&s_m, 1);
          if (ix < CAND_CAP) s_cand[ix] = ((u64)k << 32) | (uint32_t)(P_BOX - p);
        }
      }
    }
  }
  __syncthreads();
  M = min(s_m, CAND_CAP);
  int nsel = min(M, TOPK);
  for (int ci = t; ci < M; ci += NTH) {
    u64 mine = s_cand[ci];
    int r = 0;
    for (int j = 0; j < M; ++j) r += (s_cand[j] > mine) ? 1 : 0;
    if (r < TOPK) s_sel[r] = mine;
  }
  __syncthreads();
  if (t < nsel) {
    u64 w = s_sel[t];
    uint32_t k = (uint32_t)(w >> 32);
    int p = P_BOX - (int)(uint32_t)(w & 0xFFFFFFFFull);
    float4 bx = decode_box(((const float4*)priors)[p],
                           ((const float4*)loc)[(size_t)b * P_BOX + p]);
    s_box[t] = bx;
    s_area[t] = (bx.z - bx.x) * (bx.w - bx.y);
    s_score[t] = key_score(k + NORM);
  } else {
    s_box[t] = make_float4(0.f, 0.f, 0.f, 0.f);
    s_area[t] = 0.f;
    s_score[t] = 0.f;
  }
  for (int i = t; i < TOPK * 4; i += NTH) s_sup[i] = 0ull;
  __syncthreads();
  {
    int wv = t >> 6, l = t & 63;
    float4 bj[4];
    float aj[4];
#pragma unroll
    for (int cc = 0; cc < 4; ++cc) {
      bj[cc] = s_box[cc * 64 + l];
      aj[cc] = s_area[cc * 64 + l];
    }
    int cmax = (nsel + 63) >> 6;
    for (int i = wv; i < nsel; i += 4) {
      float4 bi = s_box[i];
      float ai = s_area[i];
      int c0 = i >> 6;
      for (int cc = c0; cc < cmax; ++cc) {
        int j = cc * 64 + l;
        float lx = fmaxf(bi.x, bj[cc].x), ly = fmaxf(bi.y, bj[cc].y);
        float rx = fminf(bi.z, bj[cc].z), ry = fminf(bi.w, bj[cc].w);
        float iw = fmaxf(rx - lx, 0.0f), ih = fmaxf(ry - ly, 0.0f);
        float inter = iw * ih;
        float uni = ai + aj[cc] - inter;
        float iou = inter / fmaxf(uni, 1e-12f);
        bool sup = (j > i) && (j < nsel) && (iou > 0.45f);
        u64 m = __ballot(sup);
        if (l == 0) s_sup[i * 4 + cc] = m;
      }
    }
  }
  __syncthreads();
  if (t == 0) {
    u64 aw0, aw1, aw2, aw3;
    int r0 = nsel, r1b = nsel - 64, r2b = nsel - 128, r3b = nsel - 192;
    aw0 = r0 >= 64 ? ~0ull : (r0 <= 0 ? 0ull : ((1ull << r0) - 1));
    aw1 = r1b >= 64 ? ~0ull : (r1b <= 0 ? 0ull : ((1ull << r1b) - 1));
    aw2 = r2b >= 64 ? ~0ull : (r2b <= 0 ? 0ull : ((1ull << r2b) - 1));
    aw3 = r3b >= 64 ? ~0ull : (r3b <= 0 ? 0ull : ((1ull << r3b) - 1));
    for (int i = 0; i < nsel; ++i) {
      int w = i >> 6;
      u64 cur = (w == 0) ? aw0 : (w == 1) ? aw1 : (w == 2) ? aw2 : aw3;
      if ((cur >> (i & 63)) & 1ull) {
        aw0 &= ~s_sup[i * 4 + 0]; aw1 &= ~s_sup[i * 4 + 1];
        aw2 &= ~s_sup[i * 4 + 2]; aw3 &= ~s_sup[i * 4 + 3];
      }
    }
    s_alive[0] = aw0; s_alive[1] = aw1; s_alive[2] = aw2; s_alive[3] = aw3;
  }
  __syncthreads();
  u64 w0 = s_alive[0], w1 = s_alive[1], w2 = s_alive[2], w3 = s_alive[3];
  int pc0 = __popcll(w0), pc01 = pc0 + __popcll(w1), pc012 = pc01 + __popcll(w2);
  int nk = pc012 + __popcll(w3);
  if (t < nsel) {
    int word = t >> 6, bit = t & 63;
    u64 wt = (word == 0) ? w0 : (word == 1) ? w1 : (word == 2) ? w2 : w3;
    if ((wt >> bit) & 1ull) {
      int base = (word == 0) ? 0 : (word == 1) ? pc0 : (word == 2) ? pc01 : pc012;
      int r = base + __popcll(wt & ((1ull << bit) - 1ull));
      s_kept[r] = (short)t;
    }
  }
  __syncthreads();
  if (t < TOPK) {
    float r0 = 0.f, r1b = 0.f, r2b = 0.f, r3b = 0.f, r4 = 0.f;
    if (t < nk) {
      int j = s_kept[t];
      r0 = s_score[j];
      float4 bx = s_box[j];
      r1b = bx.x; r2b = bx.y; r3b = bx.z; r4 = bx.w;
    }
    s_rows[t * 5 + 0] = r0; s_rows[t * 5 + 1] = r1b; s_rows[t * 5 + 2] = r2b;
    s_rows[t * 5 + 3] = r3b; s_rows[t * 5 + 4] = r4;
  }
  __syncthreads();
  for (int i = t; i < TOPK * 5 / 4; i += NTH)
    ((float4*)ob)[i] = ((float4*)s_rows)[i];
}

extern "C" void kernel_launch(void* const* d_in, const int* in_sizes, int n_in,
                              void* d_out, int out_size, void* d_ws, size_t ws_size,
                              hipStream_t stream) {
  (void)in_sizes;
  (void)n_in;
  (void)out_size;
  const float* loc = (const float*)d_in[0];     // [B,P,4]
  const float* conf = (const float*)d_in[1];    // [B,P,21]
  const float* priors = (const float*)d_in[2];  // [P,4]
  float* out = (float*)d_out;                   // [B,21,200,5]

  size_t keys_bytes = (size_t)BATCH * NFG * P_BOX * sizeof(uint32_t);  // 22.35 MB
  size_t sel_bytes = (size_t)BATCH * NFG * TOPK * sizeof(u64);         // 1.02 MB
  size_t nsel_bytes = (size_t)BATCH * NFG * sizeof(int);               // 2.5 KB
  size_t mask_bytes = (size_t)BATCH * NFG * TOPK * 4 * sizeof(u64);    // 4.10 MB
  if (ws_size >= keys_bytes + sel_bytes + nsel_bytes + mask_bytes) {
    char* wp = (char*)d_ws;
    uint32_t* keys = (uint32_t*)wp;
    u64* g_sel = (u64*)(wp + keys_bytes);
    int* g_nsel = (int*)(wp + keys_bytes + sel_bytes);
    u64* g_mask = (u64*)(wp + keys_bytes + sel_bytes + nsel_bytes);
    int nprep = (NBOX_TOTAL + 255) / 256;
    prep_kernel<<<nprep, 256, 0, stream>>>(loc, conf, priors, keys);
    select_kernel<<<BATCH * NFG, NTH, 0, stream>>>(keys, g_sel, g_nsel);
    maskgen_kernel<<<BATCH * NFG * 4, NTH, 0, stream>>>(loc, priors, g_sel, g_nsel, g_mask);
    finalize_kernel<<<BATCH * NCLS, NTH, 0, stream>>>(loc, priors, g_sel, g_nsel, g_mask, out);
  } else {
    nms_fused_kernel<<<BATCH * NCLS, NTH, 0, stream>>>(loc, conf, priors, out);
  }
}

// Round 8
// 133.241 us; speedup vs baseline: 1.4249x; 1.0503x over previous
//
#include <hip/hip_runtime.h>
#include <cstdint>

#define P_BOX 8732
#define NBOX_TOTAL 279424  // 32*8732
#define BATCH 32
#define NCLS 21
#define NFG 20
#define TOPK 200
#define NTH 256
#define NCH 9  // chunks of 1024 keys; chunk 8 partial (t < 135)
#define CAND_CAP 512
#define NBKT 2048
#define NORM 0xBC23D70Bu  // score_key(0.01f)+1 ; stored keys are pre-normalized
#define LIM (1u << 26)    // normalized key < LIM  <=>  eligible (score > 0.01)
#define CONF_F4 1466976   // 32*8732*21/4

typedef unsigned long long u64;

__device__ __forceinline__ uint32_t score_key(float m) {
  uint32_t b = __float_as_uint(m);
  return (b & 0x80000000u) ? ~b : (b | 0x80000000u);
}
__device__ __forceinline__ float key_score(uint32_t k) {
  uint32_t b = (k & 0x80000000u) ? (k ^ 0x80000000u) : ~k;
  return __uint_as_float(b);
}

// Exactly mirrors reference _decode (fp32).
__device__ __forceinline__ float4 decode_box(const float4 pr, const float4 lc) {
  float px = fmaxf(pr.x, 1e-6f), py = fmaxf(pr.y, 1e-6f);
  float pw = fmaxf(pr.z, 1e-6f), ph = fmaxf(pr.w, 1e-6f);
  float cx = px + lc.x * 0.1f * pw;
  float cy = py + lc.y * 0.1f * ph;
  float lw = fminf(fmaxf(lc.z * 0.2f, -4.0f), 4.0f);
  float lh = fminf(fmaxf(lc.w * 0.2f, -4.0f), 4.0f);
  float w = pw * expf(lw);
  float h = ph * expf(lh);
  float4 r;
  r.x = fminf(fmaxf(cx - 0.5f * w, 0.0f), 1.0f);
  r.y = fminf(fmaxf(cy - 0.5f * h, 0.0f), 1.0f);
  r.z = fminf(fmaxf(cx + 0.5f * w, 0.0f), 1.0f);
  r.w = fminf(fmaxf(cy + 0.5f * h, 0.0f), 1.0f);
  return r;
}

// Prep: 256 boxes/block. Stage conf in LDS; emit normalized masked score-keys,
// class-major: keys[(b*20 + c-1)*P_BOX + p].
__global__ __launch_bounds__(256) void prep_kernel(
    const float* __restrict__ loc, const float* __restrict__ conf,
    const float* __restrict__ priors, uint32_t* __restrict__ keys) {
  __shared__ float s_conf[256 * 21];
  const int t = threadIdx.x;
  const int blk = blockIdx.x;
  const float4* cf4 = (const float4*)conf;
  size_t base4 = (size_t)blk * 1344;
#pragma unroll
  for (int i = t; i < 1344; i += 256) {
    size_t g4 = base4 + i;
    if (g4 < CONF_F4) ((float4*)s_conf)[i] = cf4[g4];
  }
  __syncthreads();
  int g = blk * 256 + t;
  if (g >= NBOX_TOTAL) return;
  int b = g / P_BOX, p = g - b * P_BOX;
  float x[NCLS];
  float mx = -1e30f;
#pragma unroll
  for (int i = 0; i < NCLS; ++i) {
    float v = fminf(fmaxf(s_conf[t * 21 + i], -100.0f), 100.0f);
    x[i] = v;
    mx = fmaxf(mx, v);
  }
  float s = 0.0f;
#pragma unroll
  for (int i = 0; i < NCLS; ++i) {
    x[i] = expf(x[i] - mx);
    s += x[i];
  }
  float4 bx = decode_box(((const float4*)priors)[p], ((const float4*)loc)[g]);
  bool bok = (bx.z > bx.x + 1e-6f) && (bx.w > bx.y + 1e-6f);
#pragma unroll
  for (int ci = 1; ci < NCLS; ++ci) {
    float sc = x[ci] / s;
    float m = (bok && sc > 0.01f) ? sc : -1.0f;
    keys[((size_t)(b * NFG) + (ci - 1)) * P_BOX + p] = score_key(m) - NORM;
  }
}

__device__ __forceinline__ int cnt_ge(const uint32_t* kv, uint32_t X) {
  int n = 0;
#pragma unroll
  for (int j = 0; j < NCH * 4; ++j) n += (kv[j] >= X && kv[j] < LIM) ? 1 : 0;
  return n;
}
__device__ __forceinline__ int cnt_eq_idx(const uint32_t* kv, int t, uint32_t T, uint32_t I) {
  int n = 0;
#pragma unroll
  for (int ch = 0; ch < NCH; ++ch) {
#pragma unroll
    for (int e = 0; e < 4; ++e) {
      int p = ch * 1024 + t * 4 + e;
      n += (kv[ch * 4 + e] == T && (uint32_t)(P_BOX - p) >= I) ? 1 : 0;
    }
  }
  return n;
}

__device__ __forceinline__ int block_count(int v, int t, int* s_cnt, int& it) {
#pragma unroll
  for (int o = 32; o > 0; o >>= 1) v += __shfl_down(v, o, 64);
  int slot = it % 3;
  if (t == 0) s_cnt[(it + 1) % 3] = 0;
  if ((t & 63) == 0) atomicAdd(&s_cnt[slot], v);
  __syncthreads();
  int r = s_cnt[slot];
  ++it;
  return r;
}

__device__ __forceinline__ int3 select_bucket(const int* s_hist, int* s_S,
                                              int* s_wt, int* s_res, int need,
                                              int t) {
  const int BPT = NBKT / NTH;  // 8
  int base = t * BPT;
  int ps = 0;
#pragma unroll
  for (int i = 0; i < BPT; ++i) ps += s_hist[base + i];
  int l = t & 63, w = t >> 6;
  int v = ps;
#pragma unroll
  for (int off = 1; off < 64; off <<= 1) {
    int o = __shfl_down(v, off, 64);
    v += (l + off < 64) ? o : 0;
  }
  if (l == 0) s_wt[w] = v;
  __syncthreads();
  int hi = 0;
#pragma unroll
  for (int w2 = 0; w2 < NTH / 64; ++w2) hi += (w2 > w) ? s_wt[w2] : 0;
  int S = v + hi;
  s_S[t] = S;
  __syncthreads();
  if (t == 0 && s_S[0] < need) {
    s_res[0] = 0; s_res[1] = s_S[0]; s_res[2] = 0;
  } else if (s_S[t] >= need && (t == NTH - 1 || s_S[t + 1] < need)) {
    int suf = (t == NTH - 1) ? 0 : s_S[t + 1];
    int B = base, M = 0;
    for (int j = base + BPT - 1; j >= base; --j) {
      suf += s_hist[j];
      if (suf >= need) { B = j; M = suf; break; }
    }
    s_res[0] = B; s_res[1] = M; s_res[2] = M - s_hist[B];
  }
  __syncthreads();
  return make_int3(s_res[0], s_res[1], s_res[2]);
}

// ---------- Fused per-task kernel: select + column NMS + output ----------
// grid = 672 (b*21 + c). USE_WS: read precomputed keys; else recompute.
template <bool USE_WS>
__global__ __launch_bounds__(256) void task_kernel(
    const float* __restrict__ loc, const float* __restrict__ conf,
    const float* __restrict__ priors, const uint32_t* __restrict__ keys,
    float* __restrict__ out) {
  const int t = threadIdx.x;
  const int task = blockIdx.x;
  const int b = task / NCLS, c = task - b * NCLS;
  float* ob = out + (size_t)task * TOPK * 5;

  if (c == 0) {  // background class: all-zero rows
    float4 z = make_float4(0.f, 0.f, 0.f, 0.f);
    for (int i = t; i < TOPK * 5 / 4; i += NTH) ((float4*)ob)[i] = z;
    return;
  }
  const int ft = b * NFG + (c - 1);

  __shared__ alignas(16) int s_hist[NBKT];      // 8 KB; aliased by s_out later
  __shared__ alignas(16) u64 s_cand[CAND_CAP];  // 4 KB; aliased by s_S
  __shared__ u64 s_sel[TOPK];
  __shared__ float4 s_box[TOPK];
  __shared__ float s_area[TOPK];
  __shared__ float s_score[TOPK];
  __shared__ u64 s_alive[4];
  __shared__ u64 s_nxt[4];
  __shared__ int s_chg;
  __shared__ short s_kept[TOPK];
  __shared__ int s_wt[NTH / 64];
  __shared__ int s_res[3];
  __shared__ int s_cnt[3];
  __shared__ int s_m;
  int* s_S = (int*)s_cand;       // selection scratch
  float* s_out = (float*)s_hist;  // epilogue staging (4000 B < 8192 B)

  if (t == 0) { s_cnt[0] = 0; s_cnt[1] = 0; s_cnt[2] = 0; s_m = 0; }
  for (int i = t; i < NBKT; i += NTH) s_hist[i] = 0;

  // ---- keys into registers (36/thread) ----
  uint32_t kv[NCH * 4];
  if (USE_WS) {
    const uint4* kp = (const uint4*)(keys + (size_t)ft * P_BOX);
#pragma unroll
    for (int ch = 0; ch < 8; ++ch) {
      uint4 v = kp[ch * 256 + t];
      kv[ch * 4 + 0] = v.x; kv[ch * 4 + 1] = v.y;
      kv[ch * 4 + 2] = v.z; kv[ch * 4 + 3] = v.w;
    }
    if (t < 135) {
      uint4 v = kp[2048 + t];
      kv[32] = v.x; kv[33] = v.y; kv[34] = v.z; kv[35] = v.w;
    } else {
      kv[32] = LIM; kv[33] = LIM; kv[34] = LIM; kv[35] = LIM;
    }
  } else {
    for (int ch = 0; ch < NCH; ++ch) {
      int p0 = ch * 1024 + 4 * t;
#pragma unroll
      for (int e = 0; e < 4; ++e) {
        int p = p0 + e;
        uint32_t k = LIM;
        if (p < P_BOX) {
          const float* cf = conf + (size_t)(b * P_BOX + p) * NCLS;
          float x[NCLS];
          float mx = -1e30f;
#pragma unroll
          for (int i = 0; i < NCLS; ++i) {
            float v = fminf(fmaxf(cf[i], -100.0f), 100.0f);
            x[i] = v;
            mx = fmaxf(mx, v);
          }
          float ssum = 0.0f, ec = 0.0f;
#pragma unroll
          for (int i = 0; i < NCLS; ++i) {
            float ex = expf(x[i] - mx);
            ssum += ex;
            if (i == c) ec = ex;
          }
          float sc = ec / ssum;
          float4 bx = decode_box(((const float4*)priors)[p],
                                 ((const float4*)loc)[(size_t)b * P_BOX + p]);
          bool valid = (sc > 0.01f) && (bx.z > bx.x + 1e-6f) && (bx.w > bx.y + 1e-6f);
          k = score_key(valid ? sc : -1.0f) - NORM;
        }
        kv[ch * 4 + e] = k;
      }
    }
  }
  __syncthreads();

  // ---- 2048-bucket histogram of key bits [25:15] ----
#pragma unroll
  for (int j = 0; j < NCH * 4; ++j)
    if (kv[j] < LIM) atomicAdd(&s_hist[kv[j] >> 15], 1);
  __syncthreads();
  int3 r1 = select_bucket(s_hist, s_S, s_wt, s_res, TOPK, t);
  uint32_t Tp = (uint32_t)r1.x << 15;
  int M = r1.y;
  bool ex = false;
  uint32_t Tex = 0, I = 0;

  if (M > CAND_CAP) {  // rare: refine (width-16 sub-buckets)
    uint32_t B1 = (uint32_t)r1.x;
    int above1 = r1.z;
    __syncthreads();
    for (int i = t; i < NBKT; i += NTH) s_hist[i] = 0;
    __syncthreads();
#pragma unroll
    for (int j = 0; j < NCH * 4; ++j)
      if (kv[j] < LIM && (kv[j] >> 15) == B1)
        atomicAdd(&s_hist[(kv[j] >> 4) & (NBKT - 1)], 1);
    __syncthreads();
    int3 r2 = select_bucket(s_hist, s_S, s_wt, s_res, TOPK - above1, t);
    Tp = (B1 << 15) + ((uint32_t)r2.x << 4);
    M = above1 + r2.y;
    if (M > CAND_CAP) {  // pathological ties: exact key + index refinement
      int it = 0;
      uint32_t lo = Tp, hi = LIM;
      while (hi - lo > 1) {
        uint32_t mid = lo + ((hi - lo) >> 1);
        int cnt = block_count(cnt_ge(kv, mid), t, s_cnt, it);
        if (cnt >= TOPK) lo = mid; else hi = mid;
      }
      Tex = lo;
      int G = block_count(cnt_ge(kv, Tex + 1), t, s_cnt, it);
      int R = TOPK - G;
      uint32_t lo2 = 1, hi2 = P_BOX + 1;
      while (hi2 - lo2 > 1) {
        uint32_t mid = lo2 + ((hi2 - lo2) >> 1);
        int cnt = block_count(cnt_eq_idx(kv, t, Tex, mid), t, s_cnt, it);
        if (cnt >= R) lo2 = mid; else hi2 = mid;
      }
      I = lo2;
      ex = true;
    }
  }
  __syncthreads();

  // ---- gather candidates ----
#pragma unroll
  for (int ch = 0; ch < NCH; ++ch) {
#pragma unroll
    for (int e = 0; e < 4; ++e) {
      uint32_t k = kv[ch * 4 + e];
      if (k < LIM) {
        int p = ch * 1024 + 4 * t + e;
        bool take = ex ? (k > Tex || (k == Tex && (uint32_t)(P_BOX - p) >= I))
                       : (k >= Tp);
        if (take) {
          int ix = atomicAdd(&s_m, 1);
          if (ix < CAND_CAP) s_cand[ix] = ((u64)k << 32) | (uint32_t)(P_BOX - p);
        }
      }
    }
  }
  __syncthreads();
  M = min(s_m, CAND_CAP);
  int nsel = min(M, TOPK);

  // ---- rank (exact order; ties by smaller p) -> s_sel ----
  for (int ci = t; ci < M; ci += NTH) {
    u64 mine = s_cand[ci];
    int r = 0;
    int j = 0;
    for (; j + 8 <= M; j += 8) {
      u64 a0 = s_cand[j + 0], a1 = s_cand[j + 1], a2 = s_cand[j + 2],
          a3 = s_cand[j + 3], a4 = s_cand[j + 4], a5 = s_cand[j + 5],
          a6 = s_cand[j + 6], a7 = s_cand[j + 7];
      r += (a0 > mine) + (a1 > mine) + (a2 > mine) + (a3 > mine) +
           (a4 > mine) + (a5 > mine) + (a6 > mine) + (a7 > mine);
    }
    for (; j < M; ++j) r += (s_cand[j] > mine) ? 1 : 0;
    if (r < TOPK) s_sel[r] = mine;
  }
  __syncthreads();

  // ---- decode selected ----
  if (t < TOPK) {
    if (t < nsel) {
      u64 w = s_sel[t];
      uint32_t k = (uint32_t)(w >> 32);
      int p = P_BOX - (int)(uint32_t)(w & 0xFFFFFFFFull);
      float4 bx = decode_box(((const float4*)priors)[p],
                             ((const float4*)loc)[(size_t)b * P_BOX + p]);
      s_box[t] = bx;
      s_area[t] = (bx.z - bx.x) * (bx.w - bx.y);
      s_score[t] = key_score(k + NORM);
    } else {
      s_box[t] = make_float4(0.f, 0.f, 0.f, 0.f);
      s_area[t] = 0.f;
      s_score[t] = 0.f;
    }
  }
  __syncthreads();

  // ---- column suppression masks in registers (broadcast LDS reads) ----
  // cm[w] bit k set iff box i=w*64+k suppresses column j=t (i<j, iou>0.45)
  float4 bj = make_float4(0.f, 0.f, 0.f, 0.f);
  float aj = 0.f;
  const bool validj = (t < nsel);
  if (validj) { bj = s_box[t]; aj = s_area[t]; }
  u64 cm0 = 0, cm1 = 0, cm2 = 0, cm3 = 0;
#pragma unroll
  for (int band = 0; band < 4; ++band) {
    const int base = band * 64;
    const int iend = min(base + 64, nsel);
    u64 w = 0;
#pragma unroll 4
    for (int i = base; i < iend; ++i) {
      float4 bi = s_box[i];  // same-addr broadcast — conflict-free
      float ai = s_area[i];
      float lx = fmaxf(bi.x, bj.x), ly = fmaxf(bi.y, bj.y);
      float rx = fminf(bi.z, bj.z), ry = fminf(bi.w, bj.w);
      float iw = fmaxf(rx - lx, 0.0f), ih = fmaxf(ry - ly, 0.0f);
      float inter = iw * ih;
      float uni = ai + aj - inter;
      float iou = inter / fmaxf(uni, 1e-12f);
      bool sup = (i < t) && validj && (iou > 0.45f);
      w |= ((u64)sup) << (i - base);
    }
    if (band == 0) cm0 = w; else if (band == 1) cm1 = w;
    else if (band == 2) cm2 = w; else cm3 = w;
  }

  // ---- valid bitmap + column-Jacobi fixpoint ----
  int q0 = nsel, q1 = nsel - 64, q2 = nsel - 128, q3 = nsel - 192;
  u64 v0 = q0 >= 64 ? ~0ull : (q0 <= 0 ? 0ull : ((1ull << q0) - 1));
  u64 v1 = q1 >= 64 ? ~0ull : (q1 <= 0 ? 0ull : ((1ull << q1) - 1));
  u64 v2 = q2 >= 64 ? ~0ull : (q2 <= 0 ? 0ull : ((1ull << q2) - 1));
  u64 v3 = q3 >= 64 ? ~0ull : (q3 <= 0 ? 0ull : ((1ull << q3) - 1));
  if (t == 0) { s_alive[0] = v0; s_alive[1] = v1; s_alive[2] = v2; s_alive[3] = v3; }
  __syncthreads();

  // alive[j] = valid[j] & !OR_i(alive[i] & sup[i][j]) — fixpoint == greedy NMS
  for (int it2 = 0; it2 <= TOPK; ++it2) {
    u64 a0 = s_alive[0], a1 = s_alive[1], a2 = s_alive[2], a3 = s_alive[3];
    bool sup = ((cm0 & a0) | (cm1 & a1) | (cm2 & a2) | (cm3 & a3)) != 0ull;
    bool na = validj && !sup;
    u64 m = __ballot(na);
    if ((t & 63) == 0) s_nxt[t >> 6] = m;
    __syncthreads();
    if (t == 0) {
      s_chg = (s_nxt[0] != a0) || (s_nxt[1] != a1) ||
              (s_nxt[2] != a2) || (s_nxt[3] != a3);
      s_alive[0] = s_nxt[0]; s_alive[1] = s_nxt[1];
      s_alive[2] = s_nxt[2]; s_alive[3] = s_nxt[3];
    }
    __syncthreads();
    if (!s_chg) break;
  }

  // ---- compact kept to front via popcount ranks ----
  u64 w0 = s_alive[0], w1 = s_alive[1], w2 = s_alive[2], w3 = s_alive[3];
  int pc0 = __popcll(w0), pc01 = pc0 + __popcll(w1), pc012 = pc01 + __popcll(w2);
  int nk = pc012 + __popcll(w3);
  if (t < nsel) {
    int word = t >> 6, bit = t & 63;
    u64 wt = (word == 0) ? w0 : (word == 1) ? w1 : (word == 2) ? w2 : w3;
    if ((wt >> bit) & 1ull) {
      int base = (word == 0) ? 0 : (word == 1) ? pc0 : (word == 2) ? pc01 : pc012;
      int r = base + __popcll(wt & ((1ull << bit) - 1ull));
      s_kept[r] = (short)t;
    }
  }
  __syncthreads();  // also: s_hist (alias s_out) fully dead by here

  // ---- stage rows, coalesced store ----
  if (t < TOPK) {
    float o0 = 0.f, o1 = 0.f, o2 = 0.f, o3 = 0.f, o4 = 0.f;
    if (t < nk) {
      int j = s_kept[t];
      o0 = s_score[j];
      float4 bx = s_box[j];
      o1 = bx.x; o2 = bx.y; o3 = bx.z; o4 = bx.w;
    }
    s_out[t * 5 + 0] = o0; s_out[t * 5 + 1] = o1; s_out[t * 5 + 2] = o2;
    s_out[t * 5 + 3] = o3; s_out[t * 5 + 4] = o4;
  }
  __syncthreads();
  for (int i = t; i < TOPK * 5 / 4; i += NTH)
    ((float4*)ob)[i] = ((float4*)s_out)[i];
}

extern "C" void kernel_launch(void* const* d_in, const int* in_sizes, int n_in,
                              void* d_out, int out_size, void* d_ws, size_t ws_size,
                              hipStream_t stream) {
  (void)in_sizes;
  (void)n_in;
  (void)out_size;
  const float* loc = (const float*)d_in[0];     // [B,P,4]
  const float* conf = (const float*)d_in[1];    // [B,P,21]
  const float* priors = (const float*)d_in[2];  // [P,4]
  float* out = (float*)d_out;                   // [B,21,200,5]

  size_t keys_bytes = (size_t)BATCH * NFG * P_BOX * sizeof(uint32_t);  // 22.35 MB
  if (ws_size >= keys_bytes) {
    uint32_t* keys = (uint32_t*)d_ws;
    int nprep = (NBOX_TOTAL + 255) / 256;
    prep_kernel<<<nprep, 256, 0, stream>>>(loc, conf, priors, keys);
    task_kernel<true><<<BATCH * NCLS, NTH, 0, stream>>>(loc, conf, priors, keys, out);
  } else {
    task_kernel<false><<<BATCH * NCLS, NTH, 0, stream>>>(loc, conf, priors, nullptr, out);
  }
}

// Round 9
// 127.718 us; speedup vs baseline: 1.4865x; 1.0432x over previous
//
#include <hip/hip_runtime.h>
#include <cstdint>

#define P_BOX 8732
#define NBOX_TOTAL 279424  // 32*8732
#define BATCH 32
#define NCLS 21
#define NFG 20
#define TOPK 200
#define NTH 256
#define NCH 9  // chunks of 1024 keys; chunk 8 partial (t < 135)
#define CAND_CAP 512
#define NBKT 2048
#define NORM 0xBC23D70Bu  // score_key(0.01f)+1 ; stored keys are pre-normalized
#define LIM (1u << 26)    // normalized key < LIM  <=>  eligible (score > 0.01)
#define CONF_F4 1466976   // 32*8732*21/4

typedef unsigned long long u64;

__device__ __forceinline__ uint32_t score_key(float m) {
  uint32_t b = __float_as_uint(m);
  return (b & 0x80000000u) ? ~b : (b | 0x80000000u);
}
__device__ __forceinline__ float key_score(uint32_t k) {
  uint32_t b = (k & 0x80000000u) ? (k ^ 0x80000000u) : ~k;
  return __uint_as_float(b);
}

// Exactly mirrors reference _decode (fp32).
__device__ __forceinline__ float4 decode_box(const float4 pr, const float4 lc) {
  float px = fmaxf(pr.x, 1e-6f), py = fmaxf(pr.y, 1e-6f);
  float pw = fmaxf(pr.z, 1e-6f), ph = fmaxf(pr.w, 1e-6f);
  float cx = px + lc.x * 0.1f * pw;
  float cy = py + lc.y * 0.1f * ph;
  float lw = fminf(fmaxf(lc.z * 0.2f, -4.0f), 4.0f);
  float lh = fminf(fmaxf(lc.w * 0.2f, -4.0f), 4.0f);
  float w = pw * expf(lw);
  float h = ph * expf(lh);
  float4 r;
  r.x = fminf(fmaxf(cx - 0.5f * w, 0.0f), 1.0f);
  r.y = fminf(fmaxf(cy - 0.5f * h, 0.0f), 1.0f);
  r.z = fminf(fmaxf(cx + 0.5f * w, 0.0f), 1.0f);
  r.w = fminf(fmaxf(cy + 0.5f * h, 0.0f), 1.0f);
  return r;
}

// Prep: 256 boxes/block. Stage conf in LDS; emit normalized masked score-keys,
// class-major: keys[(b*20 + c-1)*P_BOX + p].
__global__ __launch_bounds__(256) void prep_kernel(
    const float* __restrict__ loc, const float* __restrict__ conf,
    const float* __restrict__ priors, uint32_t* __restrict__ keys) {
  __shared__ float s_conf[256 * 21];
  const int t = threadIdx.x;
  const int blk = blockIdx.x;
  const float4* cf4 = (const float4*)conf;
  size_t base4 = (size_t)blk * 1344;
#pragma unroll
  for (int i = t; i < 1344; i += 256) {
    size_t g4 = base4 + i;
    if (g4 < CONF_F4) ((float4*)s_conf)[i] = cf4[g4];
  }
  __syncthreads();
  int g = blk * 256 + t;
  if (g >= NBOX_TOTAL) return;
  int b = g / P_BOX, p = g - b * P_BOX;
  float x[NCLS];
  float mx = -1e30f;
#pragma unroll
  for (int i = 0; i < NCLS; ++i) {
    float v = fminf(fmaxf(s_conf[t * 21 + i], -100.0f), 100.0f);
    x[i] = v;
    mx = fmaxf(mx, v);
  }
  float s = 0.0f;
#pragma unroll
  for (int i = 0; i < NCLS; ++i) {
    x[i] = expf(x[i] - mx);
    s += x[i];
  }
  float4 bx = decode_box(((const float4*)priors)[p], ((const float4*)loc)[g]);
  bool bok = (bx.z > bx.x + 1e-6f) && (bx.w > bx.y + 1e-6f);
#pragma unroll
  for (int ci = 1; ci < NCLS; ++ci) {
    float sc = x[ci] / s;
    float m = (bok && sc > 0.01f) ? sc : -1.0f;
    keys[((size_t)(b * NFG) + (ci - 1)) * P_BOX + p] = score_key(m) - NORM;
  }
}

__device__ __forceinline__ int cnt_ge(const uint32_t* kv, uint32_t X) {
  int n = 0;
#pragma unroll
  for (int j = 0; j < NCH * 4; ++j) n += (kv[j] >= X && kv[j] < LIM) ? 1 : 0;
  return n;
}
__device__ __forceinline__ int cnt_eq_idx(const uint32_t* kv, int t, uint32_t T, uint32_t I) {
  int n = 0;
#pragma unroll
  for (int ch = 0; ch < NCH; ++ch) {
#pragma unroll
    for (int e = 0; e < 4; ++e) {
      int p = ch * 1024 + t * 4 + e;
      n += (kv[ch * 4 + e] == T && (uint32_t)(P_BOX - p) >= I) ? 1 : 0;
    }
  }
  return n;
}

__device__ __forceinline__ int block_count(int v, int t, int* s_cnt, int& it) {
#pragma unroll
  for (int o = 32; o > 0; o >>= 1) v += __shfl_down(v, o, 64);
  int slot = it % 3;
  if (t == 0) s_cnt[(it + 1) % 3] = 0;
  if ((t & 63) == 0) atomicAdd(&s_cnt[slot], v);
  __syncthreads();
  int r = s_cnt[slot];
  ++it;
  return r;
}

__device__ __forceinline__ int3 select_bucket(const int* s_hist, int* s_S,
                                              int* s_wt, int* s_res, int need,
                                              int t) {
  const int BPT = NBKT / NTH;  // 8
  int base = t * BPT;
  int ps = 0;
#pragma unroll
  for (int i = 0; i < BPT; ++i) ps += s_hist[base + i];
  int l = t & 63, w = t >> 6;
  int v = ps;
#pragma unroll
  for (int off = 1; off < 64; off <<= 1) {
    int o = __shfl_down(v, off, 64);
    v += (l + off < 64) ? o : 0;
  }
  if (l == 0) s_wt[w] = v;
  __syncthreads();
  int hi = 0;
#pragma unroll
  for (int w2 = 0; w2 < NTH / 64; ++w2) hi += (w2 > w) ? s_wt[w2] : 0;
  int S = v + hi;
  s_S[t] = S;
  __syncthreads();
  if (t == 0 && s_S[0] < need) {
    s_res[0] = 0; s_res[1] = s_S[0]; s_res[2] = 0;
  } else if (s_S[t] >= need && (t == NTH - 1 || s_S[t + 1] < need)) {
    int suf = (t == NTH - 1) ? 0 : s_S[t + 1];
    int B = base, M = 0;
    for (int j = base + BPT - 1; j >= base; --j) {
      suf += s_hist[j];
      if (suf >= need) { B = j; M = suf; break; }
    }
    s_res[0] = B; s_res[1] = M; s_res[2] = M - s_hist[B];
  }
  __syncthreads();
  return make_int3(s_res[0], s_res[1], s_res[2]);
}

// ---------- Fused per-task kernel: select + column NMS + output ----------
// grid = 672 (b*21 + c). USE_WS: read precomputed keys; else recompute.
template <bool USE_WS>
__global__ __launch_bounds__(256) void task_kernel(
    const float* __restrict__ loc, const float* __restrict__ conf,
    const float* __restrict__ priors, const uint32_t* __restrict__ keys,
    float* __restrict__ out) {
  const int t = threadIdx.x;
  const int task = blockIdx.x;
  const int b = task / NCLS, c = task - b * NCLS;
  float* ob = out + (size_t)task * TOPK * 5;

  if (c == 0) {  // background class: all-zero rows
    float4 z = make_float4(0.f, 0.f, 0.f, 0.f);
    for (int i = t; i < TOPK * 5 / 4; i += NTH) ((float4*)ob)[i] = z;
    return;
  }
  const int ft = b * NFG + (c - 1);

  __shared__ alignas(16) int s_hist[NBKT];      // 8 KB; aliased by s_out later
  __shared__ alignas(16) u64 s_cand[CAND_CAP];  // 4 KB; aliased by s_S
  __shared__ u64 s_sel[TOPK];
  __shared__ float4 s_box[TOPK];
  __shared__ float s_area[TOPK];
  __shared__ float s_score[TOPK];
  __shared__ u64 s_nxt[2][4];
  __shared__ short s_kept[TOPK];
  __shared__ int s_wt[NTH / 64];
  __shared__ int s_res[3];
  __shared__ int s_cnt[3];
  __shared__ int s_m;
  int* s_S = (int*)s_cand;        // selection scratch
  float* s_out = (float*)s_hist;  // epilogue staging (4000 B < 8192 B)

  if (t == 0) { s_cnt[0] = 0; s_cnt[1] = 0; s_cnt[2] = 0; s_m = 0; }
  for (int i = t; i < NBKT; i += NTH) s_hist[i] = 0;

  // ---- keys into registers (36/thread) ----
  uint32_t kv[NCH * 4];
  if (USE_WS) {
    const uint4* kp = (const uint4*)(keys + (size_t)ft * P_BOX);
#pragma unroll
    for (int ch = 0; ch < 8; ++ch) {
      uint4 v = kp[ch * 256 + t];
      kv[ch * 4 + 0] = v.x; kv[ch * 4 + 1] = v.y;
      kv[ch * 4 + 2] = v.z; kv[ch * 4 + 3] = v.w;
    }
    if (t < 135) {
      uint4 v = kp[2048 + t];
      kv[32] = v.x; kv[33] = v.y; kv[34] = v.z; kv[35] = v.w;
    } else {
      kv[32] = LIM; kv[33] = LIM; kv[34] = LIM; kv[35] = LIM;
    }
  } else {
    for (int ch = 0; ch < NCH; ++ch) {
      int p0 = ch * 1024 + 4 * t;
#pragma unroll
      for (int e = 0; e < 4; ++e) {
        int p = p0 + e;
        uint32_t k = LIM;
        if (p < P_BOX) {
          const float* cf = conf + (size_t)(b * P_BOX + p) * NCLS;
          float x[NCLS];
          float mx = -1e30f;
#pragma unroll
          for (int i = 0; i < NCLS; ++i) {
            float v = fminf(fmaxf(cf[i], -100.0f), 100.0f);
            x[i] = v;
            mx = fmaxf(mx, v);
          }
          float ssum = 0.0f, ec = 0.0f;
#pragma unroll
          for (int i = 0; i < NCLS; ++i) {
            float ex = expf(x[i] - mx);
            ssum += ex;
            if (i == c) ec = ex;
          }
          float sc = ec / ssum;
          float4 bx = decode_box(((const float4*)priors)[p],
                                 ((const float4*)loc)[(size_t)b * P_BOX + p]);
          bool valid = (sc > 0.01f) && (bx.z > bx.x + 1e-6f) && (bx.w > bx.y + 1e-6f);
          k = score_key(valid ? sc : -1.0f) - NORM;
        }
        kv[ch * 4 + e] = k;
      }
    }
  }
  __syncthreads();

  // ---- 2048-bucket histogram of key bits [25:15] ----
#pragma unroll
  for (int j = 0; j < NCH * 4; ++j)
    if (kv[j] < LIM) atomicAdd(&s_hist[kv[j] >> 15], 1);
  __syncthreads();
  int3 r1 = select_bucket(s_hist, s_S, s_wt, s_res, TOPK, t);
  uint32_t Tp = (uint32_t)r1.x << 15;
  int M = r1.y;
  bool ex = false;
  uint32_t Tex = 0, I = 0;

  if (M > CAND_CAP) {  // rare: refine (width-16 sub-buckets)
    uint32_t B1 = (uint32_t)r1.x;
    int above1 = r1.z;
    __syncthreads();
    for (int i = t; i < NBKT; i += NTH) s_hist[i] = 0;
    __syncthreads();
#pragma unroll
    for (int j = 0; j < NCH * 4; ++j)
      if (kv[j] < LIM && (kv[j] >> 15) == B1)
        atomicAdd(&s_hist[(kv[j] >> 4) & (NBKT - 1)], 1);
    __syncthreads();
    int3 r2 = select_bucket(s_hist, s_S, s_wt, s_res, TOPK - above1, t);
    Tp = (B1 << 15) + ((uint32_t)r2.x << 4);
    M = above1 + r2.y;
    if (M > CAND_CAP) {  // pathological ties: exact key + index refinement
      int it = 0;
      uint32_t lo = Tp, hi = LIM;
      while (hi - lo > 1) {
        uint32_t mid = lo + ((hi - lo) >> 1);
        int cnt = block_count(cnt_ge(kv, mid), t, s_cnt, it);
        if (cnt >= TOPK) lo = mid; else hi = mid;
      }
      Tex = lo;
      int G = block_count(cnt_ge(kv, Tex + 1), t, s_cnt, it);
      int R = TOPK - G;
      uint32_t lo2 = 1, hi2 = P_BOX + 1;
      while (hi2 - lo2 > 1) {
        uint32_t mid = lo2 + ((hi2 - lo2) >> 1);
        int cnt = block_count(cnt_eq_idx(kv, t, Tex, mid), t, s_cnt, it);
        if (cnt >= R) lo2 = mid; else hi2 = mid;
      }
      I = lo2;
      ex = true;
    }
  }
  __syncthreads();

  // ---- gather candidates: wave-ballot compaction (1 atomic per wave-slot) ----
  {
    const int lane = t & 63;
#pragma unroll
    for (int ch = 0; ch < NCH; ++ch) {
#pragma unroll
      for (int e = 0; e < 4; ++e) {
        uint32_t k = kv[ch * 4 + e];
        int p = ch * 1024 + 4 * t + e;
        bool take = (k < LIM) &&
                    (ex ? (k > Tex || (k == Tex && (uint32_t)(P_BOX - p) >= I))
                        : (k >= Tp));
        u64 m = __ballot(take);
        if (m) {
          int leader = __ffsll((long long)m) - 1;
          int base = 0;
          if (lane == leader) base = atomicAdd(&s_m, __popcll(m));
          base = __shfl(base, leader, 64);
          if (take) {
            int pre = __popcll(m & ((1ull << lane) - 1ull));
            int ix = base + pre;
            if (ix < CAND_CAP)
              s_cand[ix] = ((u64)k << 32) | (uint32_t)(P_BOX - p);
          }
        }
      }
    }
  }
  __syncthreads();
  M = min(s_m, CAND_CAP);
  int nsel = min(M, TOPK);

  // ---- rank (exact order; ties by smaller p) -> s_sel ----
  for (int ci = t; ci < M; ci += NTH) {
    u64 mine = s_cand[ci];
    int r = 0;
    int j = 0;
    for (; j + 8 <= M; j += 8) {
      u64 a0 = s_cand[j + 0], a1 = s_cand[j + 1], a2 = s_cand[j + 2],
          a3 = s_cand[j + 3], a4 = s_cand[j + 4], a5 = s_cand[j + 5],
          a6 = s_cand[j + 6], a7 = s_cand[j + 7];
      r += (a0 > mine) + (a1 > mine) + (a2 > mine) + (a3 > mine) +
           (a4 > mine) + (a5 > mine) + (a6 > mine) + (a7 > mine);
    }
    for (; j < M; ++j) r += (s_cand[j] > mine) ? 1 : 0;
    if (r < TOPK) s_sel[r] = mine;
  }
  __syncthreads();

  // ---- decode selected ----
  if (t < TOPK) {
    if (t < nsel) {
      u64 w = s_sel[t];
      uint32_t k = (uint32_t)(w >> 32);
      int p = P_BOX - (int)(uint32_t)(w & 0xFFFFFFFFull);
      float4 bx = decode_box(((const float4*)priors)[p],
                             ((const float4*)loc)[(size_t)b * P_BOX + p]);
      s_box[t] = bx;
      s_area[t] = (bx.z - bx.x) * (bx.w - bx.y);
      s_score[t] = key_score(k + NORM);
    } else {
      s_box[t] = make_float4(0.f, 0.f, 0.f, 0.f);
      s_area[t] = 0.f;
      s_score[t] = 0.f;
    }
  }
  __syncthreads();

  // ---- column suppression masks in registers (triangular: i < t only) ----
  float4 bj = make_float4(0.f, 0.f, 0.f, 0.f);
  float aj = 0.f;
  const bool validj = (t < nsel);
  if (validj) { bj = s_box[t]; aj = s_area[t]; }
  const int tcl = min(t, nsel);  // i ranges over [0, min(t, nsel))
  u64 cm0 = 0, cm1 = 0, cm2 = 0, cm3 = 0;
#pragma unroll
  for (int band = 0; band < 4; ++band) {
    const int base = band * 64;
    const int iend = min(base + 64, tcl);
    u64 w = 0;
#pragma unroll 4
    for (int i = base; i < iend; ++i) {
      float4 bi = s_box[i];  // same-addr broadcast — conflict-free
      float ai = s_area[i];
      float lx = fmaxf(bi.x, bj.x), ly = fmaxf(bi.y, bj.y);
      float rx = fminf(bi.z, bj.z), ry = fminf(bi.w, bj.w);
      float iw = fmaxf(rx - lx, 0.0f), ih = fmaxf(ry - ly, 0.0f);
      float inter = iw * ih;
      float uni = ai + aj - inter;
      float iou = inter / fmaxf(uni, 1e-12f);
      bool sup = (iou > 0.45f);
      w |= ((u64)sup) << (i - base);
    }
    if (band == 0) cm0 = w; else if (band == 1) cm1 = w;
    else if (band == 2) cm2 = w; else cm3 = w;
  }

  // ---- column-Jacobi fixpoint, alive in (uniform) registers, 1 barrier/iter ----
  // alive[j] = valid[j] & !OR_i(alive[i] & sup[i][j]) — fixpoint == greedy NMS
  int q0 = nsel, q1 = nsel - 64, q2 = nsel - 128, q3 = nsel - 192;
  u64 a0 = q0 >= 64 ? ~0ull : (q0 <= 0 ? 0ull : ((1ull << q0) - 1));
  u64 a1 = q1 >= 64 ? ~0ull : (q1 <= 0 ? 0ull : ((1ull << q1) - 1));
  u64 a2 = q2 >= 64 ? ~0ull : (q2 <= 0 ? 0ull : ((1ull << q2) - 1));
  u64 a3 = q3 >= 64 ? ~0ull : (q3 <= 0 ? 0ull : ((1ull << q3) - 1));
  for (int it2 = 0; it2 <= TOPK; ++it2) {
    bool sup = ((cm0 & a0) | (cm1 & a1) | (cm2 & a2) | (cm3 & a3)) != 0ull;
    bool na = validj && !sup;
    u64 m = __ballot(na);
    int buf = it2 & 1;
    if ((t & 63) == 0) s_nxt[buf][t >> 6] = m;
    __syncthreads();
    u64 n0 = s_nxt[buf][0], n1 = s_nxt[buf][1];
    u64 n2 = s_nxt[buf][2], n3 = s_nxt[buf][3];
    bool chg = (n0 != a0) || (n1 != a1) || (n2 != a2) || (n3 != a3);
    a0 = n0; a1 = n1; a2 = n2; a3 = n3;
    if (!chg) break;  // uniform across block (computed from shared values)
  }

  // ---- compact kept to front via popcount ranks ----
  int pc0 = __popcll(a0), pc01 = pc0 + __popcll(a1), pc012 = pc01 + __popcll(a2);
  int nk = pc012 + __popcll(a3);
  if (t < nsel) {
    int word = t >> 6, bit = t & 63;
    u64 wt = (word == 0) ? a0 : (word == 1) ? a1 : (word == 2) ? a2 : a3;
    if ((wt >> bit) & 1ull) {
      int base = (word == 0) ? 0 : (word == 1) ? pc0 : (word == 2) ? pc01 : pc012;
      int r = base + __popcll(wt & ((1ull << bit) - 1ull));
      s_kept[r] = (short)t;
    }
  }
  __syncthreads();  // also: s_hist (alias s_out) fully dead by here

  // ---- stage rows, coalesced store ----
  if (t < TOPK) {
    float o0 = 0.f, o1 = 0.f, o2 = 0.f, o3 = 0.f, o4 = 0.f;
    if (t < nk) {
      int j = s_kept[t];
      o0 = s_score[j];
      float4 bx = s_box[j];
      o1 = bx.x; o2 = bx.y; o3 = bx.z; o4 = bx.w;
    }
    s_out[t * 5 + 0] = o0; s_out[t * 5 + 1] = o1; s_out[t * 5 + 2] = o2;
    s_out[t * 5 + 3] = o3; s_out[t * 5 + 4] = o4;
  }
  __syncthreads();
  for (int i = t; i < TOPK * 5 / 4; i += NTH)
    ((float4*)ob)[i] = ((float4*)s_out)[i];
}

extern "C" void kernel_launch(void* const* d_in, const int* in_sizes, int n_in,
                              void* d_out, int out_size, void* d_ws, size_t ws_size,
                              hipStream_t stream) {
  (void)in_sizes;
  (void)n_in;
  (void)out_size;
  const float* loc = (const float*)d_in[0];     // [B,P,4]
  const float* conf = (const float*)d_in[1];    // [B,P,21]
  const float* priors = (const float*)d_in[2];  // [P,4]
  float* out = (float*)d_out;                   // [B,21,200,5]

  size_t keys_bytes = (size_t)BATCH * NFG * P_BOX * sizeof(uint32_t);  // 22.35 MB
  if (ws_size >= keys_bytes) {
    uint32_t* keys = (uint32_t*)d_ws;
    int nprep = (NBOX_TOTAL + 255) / 256;
    prep_kernel<<<nprep, 256, 0, stream>>>(loc, conf, priors, keys);
    task_kernel<true><<<BATCH * NCLS, NTH, 0, stream>>>(loc, conf, priors, keys, out);
  } else {
    task_kernel<false><<<BATCH * NCLS, NTH, 0, stream>>>(loc, conf, priors, nullptr, out);
  }
}